// Round 9
// baseline (3062.184 us; speedup 1.0000x reference)
//
#include <hip/hip_runtime.h>
#include <math.h>

#define H 64
#define F 16
#define NUM_G 128
#define DPW 8
#define L2E 1.4426950408889634f
#define TWO_L2E 2.8853900817779268f

__device__ __forceinline__ int lower_bound_i(const int* a, int n, int key) {
    int lo = 0, hi = n;
    while (lo < hi) { int mid = (lo + hi) >> 1; if (a[mid] < key) lo = mid + 1; else hi = mid; }
    return lo;
}

__device__ __forceinline__ unsigned bf16rne(float f) {
    unsigned u = __float_as_uint(f);
    return (u + 0x7fffu + ((u >> 16) & 1u)) >> 16;
}

__device__ __forceinline__ unsigned sel8u(unsigned a0, unsigned a1, unsigned a2, unsigned a3,
                                          unsigned a4, unsigned a5, unsigned a6, unsigned a7, int i) {
    unsigned b0 = (i & 1) ? a1 : a0, b1 = (i & 1) ? a3 : a2;
    unsigned b2 = (i & 1) ? a5 : a4, b3 = (i & 1) ? a7 : a6;
    unsigned c0 = (i & 2) ? b1 : b0, c1 = (i & 2) ? b3 : b2;
    return (i & 4) ? c1 : c0;
}
__device__ __forceinline__ int sel8i(int a0, int a1, int a2, int a3,
                                     int a4, int a5, int a6, int a7, int i) {
    int b0 = (i & 1) ? a1 : a0, b1 = (i & 1) ? a3 : a2;
    int b2 = (i & 1) ? a5 : a4, b3 = (i & 1) ? a7 : a6;
    int c0 = (i & 2) ? b1 : b0, c1 = (i & 2) ? b3 : b2;
    return (i & 4) ? c1 : c0;
}

// ---------------- projection section descriptor ----------------
struct ProjSec {
    const float* x; const float* Wa; const float* ba;
    const float* Wb; const float* bb2; unsigned* out;
    int N; int waveOff; float scaleA;
};
#define PROJ_ROWS 16

// ---------------- fused histogram + projections ----------------
__global__ __launch_bounds__(256) void hist_proj_kernel(
    const int* __restrict__ dst0, int E0,
    const int* __restrict__ dst1, int E1n, int dstOff1,
    int* __restrict__ cnt, int histBlocks,
    ProjSec s0, ProjSec s1, ProjSec s2, ProjSec s3, int wTot)
{
    if ((int)blockIdx.x < histBlocks) {
        int i = blockIdx.x * blockDim.x + threadIdx.x;
        if (i < E0) {
            atomicAdd(&cnt[dst0[i]], 1);
        } else {
            i -= E0;
            if (i < E1n) atomicAdd(&cnt[dstOff1 + dst1[i]], 1);
        }
        return;
    }
    const int lane = threadIdx.x & 63;
    const int w = (blockIdx.x - histBlocks) * (blockDim.x >> 6) + (threadIdx.x >> 6);
    if (w >= wTot) return;
    ProjSec S = (w >= s3.waveOff) ? s3 : (w >= s2.waveOff) ? s2 : (w >= s1.waveOff) ? s1 : s0;
    const int r0 = (w - S.waveOff) * PROJ_ROWS;
    float wa[F], wb[F];
#pragma unroll
    for (int f = 0; f < F; ++f) {
        wa[f] = S.Wa[f * H + lane] * S.scaleA;
        wb[f] = S.Wb[f * H + lane];
    }
    const float bah = S.ba[lane] * S.scaleA, bbh = S.bb2[lane];
    int r1e = r0 + PROJ_ROWS; if (r1e > S.N) r1e = S.N;
    for (int n = r0; n < r1e; ++n) {
        const float4* xr = (const float4*)(S.x + (size_t)n * F);
        float a = bah, b = bbh;
#pragma unroll
        for (int f4 = 0; f4 < F / 4; ++f4) {
            float4 t = xr[f4];
            a = fmaf(t.x, wa[4*f4+0], a); a = fmaf(t.y, wa[4*f4+1], a);
            a = fmaf(t.z, wa[4*f4+2], a); a = fmaf(t.w, wa[4*f4+3], a);
            b = fmaf(t.x, wb[4*f4+0], b); b = fmaf(t.y, wb[4*f4+1], b);
            b = fmaf(t.z, wb[4*f4+2], b); b = fmaf(t.w, wb[4*f4+3], b);
        }
        S.out[(size_t)n * H + lane] = bf16rne(a) | (bf16rne(b) << 16);
    }
}

// ---------------- scan ----------------
__global__ __launch_bounds__(256) void scan_partial(const int* __restrict__ cnt,
                                                    int* __restrict__ bsums, int n) {
    __shared__ int red[256];
    const int b = blockIdx.x, t = threadIdx.x;
    const int base = b * 2048 + t * 8;
    int s = 0;
#pragma unroll
    for (int i = 0; i < 8; ++i) { int idx = base + i; if (idx < n) s += cnt[idx]; }
    red[t] = s;
    __syncthreads();
    for (int off = 128; off > 0; off >>= 1) {
        if (t < off) red[t] += red[t + off];
        __syncthreads();
    }
    if (t == 0) bsums[b] = red[0];
}

__global__ __launch_bounds__(256) void scan_bsums(int* __restrict__ bsums, int nb) {
    __shared__ int sh[256];
    const int t = threadIdx.x;
    sh[t] = (t < nb) ? bsums[t] : 0;
    __syncthreads();
    for (int off = 1; off < 256; off <<= 1) {
        int v = sh[t];
        int add = (t >= off) ? sh[t - off] : 0;
        __syncthreads();
        sh[t] = v + add;
        __syncthreads();
    }
    if (t < nb) bsums[t] = (t == 0) ? 0 : sh[t - 1];
}

// writes offsets[idx]=prefix AND cnt[idx]=prefix (cursor init, in place)
__global__ __launch_bounds__(256) void scan_final(int* __restrict__ cnt,
                                                  const int* __restrict__ bsums,
                                                  int* __restrict__ offsets, int n) {
    __shared__ int red[256];
    const int b = blockIdx.x, t = threadIdx.x;
    const int base = b * 2048 + t * 8;
    int v[8]; int s = 0;
#pragma unroll
    for (int i = 0; i < 8; ++i) { int idx = base + i; v[i] = (idx < n) ? cnt[idx] : 0; s += v[i]; }
    red[t] = s;
    __syncthreads();
    for (int off = 1; off < 256; off <<= 1) {
        int val = red[t];
        int add = (t >= off) ? red[t - off] : 0;
        __syncthreads();
        red[t] = val + add;
        __syncthreads();
    }
    const int ex = (t == 0) ? 0 : red[t - 1];
    int run = bsums[b] + ex;
#pragma unroll
    for (int i = 0; i < 8; ++i) {
        int idx = base + i;
        if (idx < n) { offsets[idx] = run; cnt[idx] = run; }
        run += v[i];
    }
    if (t == 255 && b == gridDim.x - 1) offsets[n] = run;
}

// ---------------- pass 1: ballot-chunked partition into 8 dst-range buckets ----------------
// Bucket o's region in the staging arrays is exactly [offsets[o*perB], offsets[(o+1)*perB])
__global__ __launch_bounds__(256) void partition_kernel(
    const int* __restrict__ src0, const int* __restrict__ dst0,
    const float* __restrict__ ea0, int E0,
    const int* __restrict__ src1, const int* __restrict__ dst1,
    const float* __restrict__ ea1, int E1n,
    int dstOff1, int srcOff1, int NTd, int perB,
    const int* __restrict__ offsets, int* __restrict__ bcur,
    int2* __restrict__ t_se, int* __restrict__ t_d)
{
    int bases[8];
#pragma unroll
    for (int o = 0; o < 8; ++o) {
        int d = o * perB; if (d > NTd) d = NTd;
        bases[o] = offsets[d];
    }
    const int lane = threadIdx.x & 63;
    const unsigned long long lmask = (1ull << lane) - 1ull;
    const long ET = (long)E0 + E1n;
    const long stride = (long)gridDim.x * blockDim.x;
    long i0 = (long)blockIdx.x * blockDim.x + threadIdx.x;
    for (long iw = i0 - lane; iw < ET; iw += stride) {
        long i = iw + lane;
        bool valid = (i < ET);
        int s = 0, d = 0; float e = 0.f;
        if (valid) {
            if (i < E0) {
                s = __builtin_nontemporal_load(src0 + i);
                d = __builtin_nontemporal_load(dst0 + i);
                e = __builtin_nontemporal_load(ea0 + i);
            } else {
                long j = i - E0;
                s = __builtin_nontemporal_load(src1 + j) + srcOff1;
                d = __builtin_nontemporal_load(dst1 + j) + dstOff1;
                e = __builtin_nontemporal_load(ea1 + j);
            }
        }
        const int o = valid ? (int)((unsigned)d / (unsigned)perB) : -1;
#pragma unroll
        for (int ob = 0; ob < 8; ++ob) {
            unsigned long long m = __ballot(o == ob);
            if (m == 0ull) continue;
            const int n = __popcll(m);
            const int leader = (int)(__ffsll((long long)m) - 1);
            int pos = 0;
            if (lane == leader) pos = atomicAdd(&bcur[ob], n);
            pos = __shfl(pos, leader, 64);
            if (o == ob) {
                const int rank = __popcll(m & lmask);
                const int slot = bases[ob] + pos + rank;
                t_se[slot] = make_int2(s, __float_as_int(e));
                t_d[slot] = d;
            }
        }
    }
}

// ---------------- pass 2: within-bucket scatter (bucket = blockIdx&7 ~ XCD) ----------------
__global__ __launch_bounds__(256) void scatter_bucket_kernel(
    const int2* __restrict__ t_se, const int* __restrict__ t_d,
    const int* __restrict__ offsets, int NTd, int perB,
    int* __restrict__ cursor, int2* __restrict__ meta)
{
    const int o = blockIdx.x & 7;
    const int seg = blockIdx.x >> 3;
    const int nseg = gridDim.x >> 3;
    int dlo = o * perB; if (dlo > NTd) dlo = NTd;
    int dhi = (o + 1) * perB; if (dhi > NTd) dhi = NTd;
    const int b0 = offsets[dlo], b1 = offsets[dhi];
    const int nE = b1 - b0;
    const int e0 = b0 + (int)((long)nE * seg / nseg);
    const int e1 = b0 + (int)((long)nE * (seg + 1) / nseg);
    const int* sei = (const int*)t_se;
    for (int i = e0 + threadIdx.x; i < e1; i += 256) {
        int sx = __builtin_nontemporal_load(sei + 2 * (size_t)i);
        int sy = __builtin_nontemporal_load(sei + 2 * (size_t)i + 1);
        int d  = __builtin_nontemporal_load(t_d + i);
        int p = atomicAdd(&cursor[d], 1);
        meta[p] = make_int2(sx, sy);
    }
}

// ---------------- single-pass XCD-partitioned scatter (fallback) ----------------
__device__ __forceinline__ void scat_sub(
    const int* __restrict__ src, const int* __restrict__ dst,
    const float* __restrict__ ea, long lo, long hi,
    int dstOff, int srcOff, int dlo, int dhi,
    int* __restrict__ cursor, int2* __restrict__ meta, int tid)
{
    for (long i = lo + tid; i < hi; i += 256) {
        int d = dstOff + __builtin_nontemporal_load(dst + i);
        if (d >= dlo && d < dhi) {
            int s = __builtin_nontemporal_load(src + i) + srcOff;
            float e = __builtin_nontemporal_load(ea + i);
            int p = atomicAdd(&cursor[d], 1);
            meta[p] = make_int2(s, __float_as_int(e));
        }
    }
}

__global__ __launch_bounds__(256) void scatter_part_kernel(
    const int* __restrict__ src0, const int* __restrict__ dst0,
    const float* __restrict__ ea0, int E0,
    const int* __restrict__ src1, const int* __restrict__ dst1,
    const float* __restrict__ ea1, int E1n,
    int dstOff1, int srcOff1, int NTd,
    int* __restrict__ cursor, int2* __restrict__ meta)
{
    const int grp = blockIdx.x & 7;
    const int seg = blockIdx.x >> 3;
    const int nseg = gridDim.x >> 3;
    const int per = (NTd + 7) >> 3;
    const int dlo = grp * per;
    int dhi = dlo + per; if (dhi > NTd) dhi = NTd;
    if (dlo >= dhi) return;
    const long ET = (long)E0 + E1n;
    const long e0 = (ET * seg) / nseg;
    const long e1 = (ET * (seg + 1)) / nseg;
    const int tid = threadIdx.x;
    long a0 = e0, a1 = (e1 < E0) ? e1 : E0;
    if (a0 < a1) scat_sub(src0, dst0, ea0, a0, a1, 0, 0, dlo, dhi, cursor, meta, tid);
    long b0 = (e0 > E0) ? e0 : E0, b1 = e1;
    if (b0 < b1) scat_sub(src1, dst1, ea1, b0 - E0, b1 - E0, dstOff1, srcOff1,
                          dlo, dhi, cursor, meta, tid);
}

// ---------------- deep-pipelined streaming aggregate ----------------
struct RelP {
    const float* We; const float* be;
    const int* batch;
    float* psum;
    int Ndst;
    int offBase;
    int kskBase;
};

__global__ __launch_bounds__(256) void aggregate_v4(
    RelP P0, RelP P1, const unsigned* __restrict__ qvp,
    const unsigned* __restrict__ kskp,
    const int* __restrict__ offsets, const int2* __restrict__ meta,
    int nChunk0, int chunkHi)
{
    const int lane = threadIdx.x & 63;
    const int cid = blockIdx.x * (blockDim.x >> 6) + (threadIdx.x >> 6);
    if (cid >= chunkHi) return;
    const bool r1v = (cid >= nChunk0);
    const RelP P = r1v ? P1 : P0;
    const int dLo = (r1v ? cid - nChunk0 : cid) * DPW;
    if (dLo >= P.Ndst) return;
    const int ndst = (P.Ndst - dLo < DPW) ? (P.Ndst - dLo) : DPW;

    const float weh = P.We[lane], beh = P.be[lane];

    const int* ob = offsets + P.offBase + dLo;
    const int* bb_ = P.batch + dLo;
    int of0, of1, of2, of3, of4, of5, of6, of7, of8;
    int bg0, bg1, bg2, bg3, bg4, bg5, bg6, bg7;
#define LDO(I) __builtin_amdgcn_readfirstlane(ob[(I) < ndst ? (I) : ndst])
#define LDB(I) __builtin_amdgcn_readfirstlane(bb_[(I) < ndst ? (I) : (ndst - 1)])
    of0 = LDO(0); of1 = LDO(1); of2 = LDO(2); of3 = LDO(3); of4 = LDO(4);
    of5 = LDO(5); of6 = LDO(6); of7 = LDO(7); of8 = LDO(8);
    bg0 = LDB(0); bg1 = LDB(1); bg2 = LDB(2); bg3 = LDB(3);
    bg4 = LDB(4); bg5 = LDB(5); bg6 = LDB(6); bg7 = LDB(7);
#undef LDO
#undef LDB

    const unsigned* kb = kskp + (size_t)(P.kskBase + dLo) * H + lane;
    unsigned kp0 = kb[0], kp1 = 0, kp2 = 0, kp3 = 0, kp4 = 0, kp5 = 0, kp6 = 0, kp7 = 0;
    if (ndst > 1) kp1 = kb[1 * H];
    if (ndst > 2) kp2 = kb[2 * H];
    if (ndst > 3) kp3 = kb[3 * H];
    if (ndst > 4) kp4 = kb[4 * H];
    if (ndst > 5) kp5 = kb[5 * H];
    if (ndst > 6) kp6 = kb[6 * H];
    if (ndst > 7) kp7 = kb[7 * H];

    int idx = 0;
    float kcur = __uint_as_float(kp0 << 16);
    float skcur = __uint_as_float(kp0 & 0xffff0000u);
    int pend = of1;
    int bgcur = bg0;
    float acc = 0.f;
    const int base = of0;
    const int pstop = of8;
    const int nedges = pstop - base;
    const int ngroups = (nedges + 7) >> 3;

#define ADVANCE()                                                              \
    {                                                                          \
        float hv = fmaxf(acc + skcur, 0.f);                                    \
        atomicAdd(&P.psum[(size_t)bgcur * H + lane], hv);                      \
        ++idx;                                                                 \
        unsigned kv = sel8u(kp0, kp1, kp2, kp3, kp4, kp5, kp6, kp7, idx);      \
        kcur = __uint_as_float(kv << 16);                                      \
        skcur = __uint_as_float(kv & 0xffff0000u);                             \
        pend = sel8i(of1, of2, of3, of4, of5, of6, of7, of8, idx);             \
        bgcur = sel8i(bg0, bg1, bg2, bg3, bg4, bg5, bg6, bg7, idx);            \
        acc = 0.f;                                                             \
    }

#define ISSUE(RING, M, L8, GI)                                                 \
    if ((GI) < ngroups) {                                                      \
        _Pragma("unroll")                                                      \
        for (int j = 0; j < 8; ++j) {                                          \
            int s_ = __builtin_amdgcn_readlane((M).x, (L8) + j);               \
            RING[j] = qvp[(size_t)(unsigned)s_ * H + lane];                    \
        }                                                                      \
    }

#define CONSUME(RING, L8, GI)                                                  \
    if ((GI) < ngroups) {                                                      \
        const int e0 = (GI) * 8;                                               \
        int n_ = nedges - e0; if (n_ > 8) n_ = 8;                              \
        _Pragma("unroll")                                                      \
        for (int j = 0; j < 8; ++j) {                                          \
            if (j < n_) {                                                      \
                while (base + e0 + j >= pend) ADVANCE();                       \
                float e = fmaf(__int_as_float(                                 \
                    __builtin_amdgcn_readlane(Mc.y, (L8) + j)), weh, beh);     \
                float qq = __uint_as_float(RING[j] << 16);                     \
                float vv = __uint_as_float(RING[j] & 0xffff0000u);             \
                float g2 = fmaf(TWO_L2E, e, kcur + qq);                       \
                float sg = __builtin_amdgcn_rcpf(1.0f + __builtin_amdgcn_exp2f(-g2)); \
                acc = fmaf(sg, vv + e, acc);                                   \
            }                                                                  \
        }                                                                      \
    }

    if (nedges > 0) {
        int pos0 = base + lane; if (pos0 > pstop - 1) pos0 = pstop - 1;
        int2 Mc = meta[pos0];
        int2 Mn = Mc;
        if (nedges > 64) {
            int pos1 = base + 64 + lane; if (pos1 > pstop - 1) pos1 = pstop - 1;
            Mn = meta[pos1];
        }
        unsigned r0[8], r1[8], r2[8], r3[8];
        ISSUE(r0, Mc, 0, 0);
        ISSUE(r1, Mc, 8, 1);
        const int nsb = (ngroups + 7) >> 3;
        int sbg = 0;
        for (int sbi = 0; sbi < nsb; ++sbi, sbg += 8) {
            ISSUE(r2, Mc, 16, sbg + 2); CONSUME(r0, 0,  sbg + 0);
            ISSUE(r3, Mc, 24, sbg + 3); CONSUME(r1, 8,  sbg + 1);
            ISSUE(r0, Mc, 32, sbg + 4); CONSUME(r2, 16, sbg + 2);
            ISSUE(r1, Mc, 40, sbg + 5); CONSUME(r3, 24, sbg + 3);
            ISSUE(r2, Mc, 48, sbg + 6); CONSUME(r0, 32, sbg + 4);
            ISSUE(r3, Mc, 56, sbg + 7); CONSUME(r1, 40, sbg + 5);
            ISSUE(r0, Mn, 0,  sbg + 8); CONSUME(r2, 48, sbg + 6);
            ISSUE(r1, Mn, 8,  sbg + 9); CONSUME(r3, 56, sbg + 7);
            Mc = Mn;
            if ((sbi + 2) * 64 < nedges) {
                int pos = base + (sbi + 2) * 64 + lane;
                if (pos > pstop - 1) pos = pstop - 1;
                Mn = meta[pos];
            }
        }
    }
#undef ISSUE
#undef CONSUME

    for (;;) {
        float hv = fmaxf(acc + skcur, 0.f);
        atomicAdd(&P.psum[(size_t)bgcur * H + lane], hv);
        ++idx;
        if (idx >= ndst) break;
        unsigned kv = sel8u(kp0, kp1, kp2, kp3, kp4, kp5, kp6, kp7, idx);
        kcur = __uint_as_float(kv << 16);
        skcur = __uint_as_float(kv & 0xffff0000u);
        bgcur = sel8i(bg0, bg1, bg2, bg3, bg4, bg5, bg6, bg7, idx);
        acc = 0.f;
    }
#undef ADVANCE
}

// ---------------- MLP with fused per-graph counts ----------------
__global__ __launch_bounds__(64) void mlp_kernel(
    const float* __restrict__ sum_c, const float* __restrict__ sum_b,
    const int* __restrict__ batch_c, int Nc,
    const int* __restrict__ batch_b, int Nb,
    const float* __restrict__ W1, const float* __restrict__ b1,
    const float* __restrict__ W2, const float* __restrict__ b2,
    const float* __restrict__ W3, const float* __restrict__ b3,
    const float* __restrict__ Wout, const float* __restrict__ bout,
    float* __restrict__ out)
{
    const int g = blockIdx.x;
    const int h = threadIdx.x;
    __shared__ float pld[2 * H];
    __shared__ float hbuf[H];
    __shared__ float cnts[2];
    if (h < 2) {
        const int* a = h ? batch_b : batch_c;
        const int n = h ? Nb : Nc;
        int lo = lower_bound_i(a, n, g);
        int hi = lower_bound_i(a, n, g + 1);
        cnts[h] = fmaxf((float)(hi - lo), 1.f);
    }
    __syncthreads();
    pld[h] = sum_c[g * H + h] / cnts[0];
    pld[H + h] = sum_b[g * H + h] / cnts[1];
    __syncthreads();
    float a1 = b1[h];
    for (int j = 0; j < 2 * H; ++j) a1 = fmaf(pld[j], W1[j * H + h], a1);
    a1 = fmaxf(a1, 0.f);
    __syncthreads();
    hbuf[h] = a1;
    __syncthreads();
    float a2 = b2[h];
    for (int j = 0; j < H; ++j) a2 = fmaf(hbuf[j], W2[j * H + h], a2);
    a2 = fmaxf(a2, 0.f);
    __syncthreads();
    hbuf[h] = a2;
    __syncthreads();
    float a3 = b3[h];
    for (int j = 0; j < H; ++j) a3 = fmaf(hbuf[j], W3[j * H + h], a3);
    a3 = fmaxf(a3, 0.f);
    float p = a3 * Wout[h];
#pragma unroll
    for (int off = 32; off > 0; off >>= 1) p += __shfl_down(p, off, 64);
    if (h == 0) out[g] = p + bout[0];
}

extern "C" void kernel_launch(void* const* d_in, const int* in_sizes, int n_in,
                              void* d_out, int out_size, void* d_ws, size_t ws_size,
                              hipStream_t stream) {
    const float* x_x   = (const float*)d_in[0];
    const float* x_c   = (const float*)d_in[1];
    const float* x_b   = (const float*)d_in[2];
    const float* ea_ac = (const float*)d_in[3];
    const float* ea_cb = (const float*)d_in[4];

    const float* Wk_ac = (const float*)d_in[5];
    const float* Wq_ac = (const float*)d_in[6];
    const float* Wv_ac = (const float*)d_in[7];
    const float* Wskip_ac = (const float*)d_in[8];
    const float* We_ac = (const float*)d_in[9];
    const float* bk_ac = (const float*)d_in[10];
    const float* bq_ac = (const float*)d_in[11];
    const float* bv_ac = (const float*)d_in[12];
    const float* be_ac = (const float*)d_in[13];
    const float* bconv_ac = (const float*)d_in[14];

    const float* Wk_cb = (const float*)d_in[15];
    const float* Wq_cb = (const float*)d_in[16];
    const float* Wv_cb = (const float*)d_in[17];
    const float* Wskip_cb = (const float*)d_in[18];
    const float* We_cb = (const float*)d_in[19];
    const float* bk_cb = (const float*)d_in[20];
    const float* bq_cb = (const float*)d_in[21];
    const float* bv_cb = (const float*)d_in[22];
    const float* be_cb = (const float*)d_in[23];
    const float* bconv_cb = (const float*)d_in[24];

    const float* W1 = (const float*)d_in[25];
    const float* b1 = (const float*)d_in[26];
    const float* W2 = (const float*)d_in[27];
    const float* b2 = (const float*)d_in[28];
    const float* W3 = (const float*)d_in[29];
    const float* b3 = (const float*)d_in[30];
    const float* Wout = (const float*)d_in[31];
    const float* bout = (const float*)d_in[32];

    const int* src_ac = (const int*)d_in[33];
    const int* dst_ac = (const int*)d_in[34];
    const int* src_cb = (const int*)d_in[35];
    const int* dst_cb = (const int*)d_in[36];
    const int* batch_c = (const int*)d_in[37];
    const int* batch_b = (const int*)d_in[38];

    const int Nx = in_sizes[0] / F;
    const int Nc = in_sizes[1] / F;
    const int Nb = in_sizes[2] / F;
    const int E1 = in_sizes[33];
    const int E2 = in_sizes[35];
    (void)n_in; (void)out_size;

    const int NT = Nc + Nb;
    const size_t ET = (size_t)E1 + E2;
    const int NMAX = (Nc > Nb ? Nc : Nb);
    const int EMAX = (E1 > E2 ? E1 : E2);
    const int SRCMAX = (Nx > Nc ? Nx : Nc);
    const size_t SUMS = 2 * NUM_G * H;

    const size_t wordsA = 2 * ET + (size_t)(NT + 1) + NT + 256 + SUMS
                        + (size_t)(Nx + Nc) * H + (size_t)(Nc + Nb) * H;
    const size_t wordsA2 = wordsA + 3 * ET;          // + staging (int2 + int per edge)
    const bool pathA  = (ws_size >= wordsA * 4);
    const bool pathA2 = (ws_size >= wordsA2 * 4);

    int* ws = (int*)d_ws;
    const size_t metaN = pathA ? 2 * ET : 2 * (size_t)EMAX;
    const int nOff = pathA ? NT : NMAX;
    int2*     meta    = (int2*)ws;
    int*      offsets = ws + metaN;
    int*      cnt     = offsets + (nOff + 1);
    int*      bsums   = cnt + nOff;
    int*      bcur    = bsums + 240;                 // 8 ints inside bsums' 256 slot area (nScan<=147)
    float*    sum_c   = (float*)(bsums + 256);
    float*    sum_b   = sum_c + NUM_G * H;
    unsigned* qvp     = (unsigned*)(sum_b + NUM_G * H);
    unsigned* kskp    = qvp + (size_t)(pathA ? (Nx + Nc) : SRCMAX) * H;
    int2*     t_se    = (int2*)(kskp + (size_t)(pathA ? (Nc + Nb) : NMAX) * H);
    int*      t_d     = (int*)(t_se + ET);

    const int nC0 = (Nc + DPW - 1) / DPW;
    const int nC1 = (Nb + DPW - 1) / DPW;

    RelP P0, P1;
    P0.We = We_ac; P0.be = be_ac; P0.batch = batch_c; P0.psum = sum_c;
    P0.Ndst = Nc; P0.offBase = 0; P0.kskBase = 0;
    P1.We = We_cb; P1.be = be_cb; P1.batch = batch_b; P1.psum = sum_b;
    P1.Ndst = Nb; P1.offBase = pathA ? Nc : 0; P1.kskBase = pathA ? Nc : 0;

    if (pathA) {
        // one memset covers cnt | bsums(+bcur) | sum_c | sum_b (contiguous)
        hipMemsetAsync(cnt, 0, (size_t)(NT + 256 + SUMS) * sizeof(int), stream);

        const int nScan = (NT + 2047) / 2048;
        const int EB = (int)((ET + 255) / 256);
        const int w1 = (Nx + PROJ_ROWS - 1) / PROJ_ROWS;
        const int w2 = w1 + (Nc + PROJ_ROWS - 1) / PROJ_ROWS;
        const int w3 = w2 + (Nc + PROJ_ROWS - 1) / PROJ_ROWS;
        const int wTot = w3 + (Nb + PROJ_ROWS - 1) / PROJ_ROWS;
        ProjSec s0 = { x_x, Wq_ac, bq_ac, Wv_ac, bv_ac, qvp, Nx, 0, L2E };
        ProjSec s1 = { x_c, Wq_cb, bq_cb, Wv_cb, bv_cb, qvp + (size_t)Nx * H, Nc, w1, L2E };
        ProjSec s2 = { x_c, Wk_ac, bk_ac, Wskip_ac, bconv_ac, kskp, Nc, w2, L2E };
        ProjSec s3 = { x_b, Wk_cb, bk_cb, Wskip_cb, bconv_cb, kskp + (size_t)Nc * H, Nb, w3, L2E };
        const int projB = (wTot + 3) / 4;

        hist_proj_kernel<<<EB + projB, 256, 0, stream>>>(
            dst_ac, E1, dst_cb, E2, Nc, cnt, EB, s0, s1, s2, s3, wTot);
        scan_partial<<<nScan, 256, 0, stream>>>(cnt, bsums, NT);
        scan_bsums<<<1, 256, 0, stream>>>(bsums, nScan);
        scan_final<<<nScan, 256, 0, stream>>>(cnt, bsums, offsets, NT);

        const int perB = (NT + 7) / 8;
        if (pathA2) {
            partition_kernel<<<2048, 256, 0, stream>>>(
                src_ac, dst_ac, ea_ac, E1, src_cb, dst_cb, ea_cb, E2,
                Nc, Nx, NT, perB, offsets, bcur, t_se, t_d);
            scatter_bucket_kernel<<<2048, 256, 0, stream>>>(
                t_se, t_d, offsets, NT, perB, cnt, meta);
        } else {
            scatter_part_kernel<<<2048, 256, 0, stream>>>(
                src_ac, dst_ac, ea_ac, E1, src_cb, dst_cb, ea_cb, E2,
                Nc, Nx, NT, cnt, meta);
        }

        const int nW = nC0 + nC1;
        aggregate_v4<<<(nW + 3) / 4, 256, 0, stream>>>(
            P0, P1, qvp, kskp, offsets, meta, nC0, nW);
    } else {
        hipMemsetAsync(sum_c, 0, SUMS * sizeof(float), stream);
        for (int rel = 0; rel < 2; ++rel) {
            const int n = rel ? Nb : Nc;
            const int E = rel ? E2 : E1;
            const int Ns = rel ? Nc : Nx;
            const int* srcA = rel ? src_cb : src_ac;
            const int* dstA = rel ? dst_cb : dst_ac;
            const float* eaA = rel ? ea_cb : ea_ac;
            const float* xs = rel ? x_c : x_x;
            const float* xd = rel ? x_b : x_c;
            const float* Wq = rel ? Wq_cb : Wq_ac; const float* bq = rel ? bq_cb : bq_ac;
            const float* Wv = rel ? Wv_cb : Wv_ac; const float* bv = rel ? bv_cb : bv_ac;
            const float* Wk = rel ? Wk_cb : Wk_ac; const float* bk = rel ? bk_cb : bk_ac;
            const float* Wsk = rel ? Wskip_cb : Wskip_ac;
            const float* bcv = rel ? bconv_cb : bconv_ac;
            const int nScan = (n + 2047) / 2048;
            hipMemsetAsync(cnt, 0, n * sizeof(int), stream);
            const int w1 = (Ns + PROJ_ROWS - 1) / PROJ_ROWS;
            const int wTot = w1 + (n + PROJ_ROWS - 1) / PROJ_ROWS;
            ProjSec s0 = { xs, Wq, bq, Wv, bv, qvp, Ns, 0, L2E };
            ProjSec s1 = { xs, Wq, bq, Wv, bv, qvp, 0, w1, L2E };
            ProjSec s2 = { xd, Wk, bk, Wsk, bcv, kskp, n, w1, L2E };
            ProjSec s3 = { xd, Wk, bk, Wsk, bcv, kskp, 0, wTot, L2E };
            const int EB = (E + 255) / 256;
            const int projB = (wTot + 3) / 4;
            hist_proj_kernel<<<EB + projB, 256, 0, stream>>>(
                dstA, E, dstA, 0, 0, cnt, EB, s0, s1, s2, s3, wTot);
            scan_partial<<<nScan, 256, 0, stream>>>(cnt, bsums, n);
            scan_bsums<<<1, 256, 0, stream>>>(bsums, nScan);
            scan_final<<<nScan, 256, 0, stream>>>(cnt, bsums, offsets, n);
            scatter_part_kernel<<<2048, 256, 0, stream>>>(
                srcA, dstA, eaA, E, srcA, dstA, eaA, 0, 0, 0, n, cnt, meta);
            RelP PR = rel ? P1 : P0;
            const int nCr = rel ? nC1 : nC0;
            aggregate_v4<<<(nCr + 3) / 4, 256, 0, stream>>>(
                PR, PR, qvp, kskp, offsets, meta, nCr, nCr);
        }
    }

    mlp_kernel<<<NUM_G, 64, 0, stream>>>(
        sum_c, sum_b, batch_c, Nc, batch_b, Nb,
        W1, b1, W2, b2, W3, b3, Wout, bout, (float*)d_out);
}

// Round 10
// 692.620 us; speedup vs baseline: 4.4212x; 4.4212x over previous
//
#include <hip/hip_runtime.h>
#include <math.h>

#define H 64
#define F 16
#define NUM_G 128
#define DPW 8
#define NBLK 2048
#define L2E 1.4426950408889634f
#define TWO_L2E 2.8853900817779268f

__device__ __forceinline__ int lower_bound_i(const int* a, int n, int key) {
    int lo = 0, hi = n;
    while (lo < hi) { int mid = (lo + hi) >> 1; if (a[mid] < key) lo = mid + 1; else hi = mid; }
    return lo;
}

__device__ __forceinline__ unsigned bf16rne(float f) {
    unsigned u = __float_as_uint(f);
    return (u + 0x7fffu + ((u >> 16) & 1u)) >> 16;
}

__device__ __forceinline__ unsigned sel8u(unsigned a0, unsigned a1, unsigned a2, unsigned a3,
                                          unsigned a4, unsigned a5, unsigned a6, unsigned a7, int i) {
    unsigned b0 = (i & 1) ? a1 : a0, b1 = (i & 1) ? a3 : a2;
    unsigned b2 = (i & 1) ? a5 : a4, b3 = (i & 1) ? a7 : a6;
    unsigned c0 = (i & 2) ? b1 : b0, c1 = (i & 2) ? b3 : b2;
    return (i & 4) ? c1 : c0;
}
__device__ __forceinline__ int sel8i(int a0, int a1, int a2, int a3,
                                     int a4, int a5, int a6, int a7, int i) {
    int b0 = (i & 1) ? a1 : a0, b1 = (i & 1) ? a3 : a2;
    int b2 = (i & 1) ? a5 : a4, b3 = (i & 1) ? a7 : a6;
    int c0 = (i & 2) ? b1 : b0, c1 = (i & 2) ? b3 : b2;
    return (i & 4) ? c1 : c0;
}

// ---------------- projection section descriptor ----------------
struct ProjSec {
    const float* x; const float* Wa; const float* ba;
    const float* Wb; const float* bb2; unsigned* out;
    int N; int waveOff; float scaleA;
};
#define PROJ_ROWS 16

// ---------------- fused histogram + projections ----------------
__global__ __launch_bounds__(256) void hist_proj_kernel(
    const int* __restrict__ dst0, int E0,
    const int* __restrict__ dst1, int E1n, int dstOff1,
    int* __restrict__ cnt, int histBlocks,
    ProjSec s0, ProjSec s1, ProjSec s2, ProjSec s3, int wTot)
{
    if ((int)blockIdx.x < histBlocks) {
        int i = blockIdx.x * blockDim.x + threadIdx.x;
        if (i < E0) {
            atomicAdd(&cnt[dst0[i]], 1);
        } else {
            i -= E0;
            if (i < E1n) atomicAdd(&cnt[dstOff1 + dst1[i]], 1);
        }
        return;
    }
    const int lane = threadIdx.x & 63;
    const int w = (blockIdx.x - histBlocks) * (blockDim.x >> 6) + (threadIdx.x >> 6);
    if (w >= wTot) return;
    ProjSec S = (w >= s3.waveOff) ? s3 : (w >= s2.waveOff) ? s2 : (w >= s1.waveOff) ? s1 : s0;
    const int r0 = (w - S.waveOff) * PROJ_ROWS;
    float wa[F], wb[F];
#pragma unroll
    for (int f = 0; f < F; ++f) {
        wa[f] = S.Wa[f * H + lane] * S.scaleA;
        wb[f] = S.Wb[f * H + lane];
    }
    const float bah = S.ba[lane] * S.scaleA, bbh = S.bb2[lane];
    int r1e = r0 + PROJ_ROWS; if (r1e > S.N) r1e = S.N;
    for (int n = r0; n < r1e; ++n) {
        const float4* xr = (const float4*)(S.x + (size_t)n * F);
        float a = bah, b = bbh;
#pragma unroll
        for (int f4 = 0; f4 < F / 4; ++f4) {
            float4 t = xr[f4];
            a = fmaf(t.x, wa[4*f4+0], a); a = fmaf(t.y, wa[4*f4+1], a);
            a = fmaf(t.z, wa[4*f4+2], a); a = fmaf(t.w, wa[4*f4+3], a);
            b = fmaf(t.x, wb[4*f4+0], b); b = fmaf(t.y, wb[4*f4+1], b);
            b = fmaf(t.z, wb[4*f4+2], b); b = fmaf(t.w, wb[4*f4+3], b);
        }
        S.out[(size_t)n * H + lane] = bf16rne(a) | (bf16rne(b) << 16);
    }
}

// ---------------- scan (per-dst offsets) ----------------
__global__ __launch_bounds__(256) void scan_partial(const int* __restrict__ cnt,
                                                    int* __restrict__ bsums, int n) {
    __shared__ int red[256];
    const int b = blockIdx.x, t = threadIdx.x;
    const int base = b * 2048 + t * 8;
    int s = 0;
#pragma unroll
    for (int i = 0; i < 8; ++i) { int idx = base + i; if (idx < n) s += cnt[idx]; }
    red[t] = s;
    __syncthreads();
    for (int off = 128; off > 0; off >>= 1) {
        if (t < off) red[t] += red[t + off];
        __syncthreads();
    }
    if (t == 0) bsums[b] = red[0];
}

__global__ __launch_bounds__(256) void scan_bsums(int* __restrict__ bsums, int nb) {
    __shared__ int sh[256];
    const int t = threadIdx.x;
    sh[t] = (t < nb) ? bsums[t] : 0;
    __syncthreads();
    for (int off = 1; off < 256; off <<= 1) {
        int v = sh[t];
        int add = (t >= off) ? sh[t - off] : 0;
        __syncthreads();
        sh[t] = v + add;
        __syncthreads();
    }
    if (t < nb) bsums[t] = (t == 0) ? 0 : sh[t - 1];
}

// writes offsets[idx]=prefix AND cnt[idx]=prefix (cursor init, in place)
__global__ __launch_bounds__(256) void scan_final(int* __restrict__ cnt,
                                                  const int* __restrict__ bsums,
                                                  int* __restrict__ offsets, int n) {
    __shared__ int red[256];
    const int b = blockIdx.x, t = threadIdx.x;
    const int base = b * 2048 + t * 8;
    int v[8]; int s = 0;
#pragma unroll
    for (int i = 0; i < 8; ++i) { int idx = base + i; v[i] = (idx < n) ? cnt[idx] : 0; s += v[i]; }
    red[t] = s;
    __syncthreads();
    for (int off = 1; off < 256; off <<= 1) {
        int val = red[t];
        int add = (t >= off) ? red[t - off] : 0;
        __syncthreads();
        red[t] = val + add;
        __syncthreads();
    }
    const int ex = (t == 0) ? 0 : red[t - 1];
    int run = bsums[b] + ex;
#pragma unroll
    for (int i = 0; i < 8; ++i) {
        int idx = base + i;
        if (idx < n) { offsets[idx] = run; cnt[idx] = run; }
        run += v[i];
    }
    if (t == 255 && b == gridDim.x - 1) offsets[n] = run;
}

// ---------------- radix pass 1a: per-block bucket histogram ----------------
__global__ __launch_bounds__(256) void bhist_kernel(
    const int* __restrict__ dst0, int E0,
    const int* __restrict__ dst1, int E1n,
    int dstOff1, int perB, int* __restrict__ bhist)
{
    __shared__ int cnt8[8];
    if (threadIdx.x < 8) cnt8[threadIdx.x] = 0;
    __syncthreads();
    const long ET = (long)E0 + E1n;
    const long e0 = ET * blockIdx.x / NBLK;
    const long e1 = ET * (blockIdx.x + 1) / NBLK;
    for (long i = e0 + threadIdx.x; i < e1; i += 256) {
        int d = (i < E0) ? __builtin_nontemporal_load(dst0 + i)
                         : dstOff1 + __builtin_nontemporal_load(dst1 + (i - E0));
        atomicAdd(&cnt8[(unsigned)d / (unsigned)perB], 1);
    }
    __syncthreads();
    if (threadIdx.x < 8) bhist[threadIdx.x * NBLK + blockIdx.x] = cnt8[threadIdx.x];
}

// ---------------- radix pass 1b helper scan: per-bucket exclusive over blocks ----------------
__global__ __launch_bounds__(512) void bscan_kernel(int* __restrict__ bhist)
{
    const int lane = threadIdx.x & 63;
    const int o = threadIdx.x >> 6;           // 8 waves, one per bucket
    int running = 0;
    for (int t = 0; t < NBLK / 64; ++t) {
        const int idx = o * NBLK + t * 64 + lane;
        const int v = bhist[idx];
        int x = v;
#pragma unroll
        for (int off = 1; off < 64; off <<= 1) {
            int nx = __shfl_up(x, off, 64);
            if (lane >= off) x += nx;
        }
        bhist[idx] = running + x - v;          // exclusive
        running += __shfl(x, 63, 64);
    }
}

// ---------------- radix pass 1c: deterministic bucketed write of staging tuples ----------------
__global__ __launch_bounds__(256) void bscatter_kernel(
    const int* __restrict__ src0, const int* __restrict__ dst0,
    const float* __restrict__ ea0, int E0,
    const int* __restrict__ src1, const int* __restrict__ dst1,
    const float* __restrict__ ea1, int E1n,
    int dstOff1, int srcOff1, int NTd, int perB,
    const int* __restrict__ offsets, const int* __restrict__ bhist,
    int2* __restrict__ t_se, int* __restrict__ t_d)
{
    __shared__ int cur8[8];
    if (threadIdx.x < 8) {
        int o = threadIdx.x;
        int d = o * perB; if (d > NTd) d = NTd;
        cur8[o] = offsets[d] + bhist[o * NBLK + blockIdx.x];
    }
    __syncthreads();
    const int lane = threadIdx.x & 63;
    const unsigned long long lmask = (1ull << lane) - 1ull;
    const long ET = (long)E0 + E1n;
    const long e0 = ET * blockIdx.x / NBLK;
    const long e1 = ET * (blockIdx.x + 1) / NBLK;
    for (long iw = e0 + (threadIdx.x - lane); iw < e1; iw += 256) {
        long i = iw + lane;
        bool valid = (i < e1);
        int s = 0, d = 0; float e = 0.f;
        if (valid) {
            if (i < E0) {
                s = __builtin_nontemporal_load(src0 + i);
                d = __builtin_nontemporal_load(dst0 + i);
                e = __builtin_nontemporal_load(ea0 + i);
            } else {
                long j = i - E0;
                s = __builtin_nontemporal_load(src1 + j) + srcOff1;
                d = __builtin_nontemporal_load(dst1 + j) + dstOff1;
                e = __builtin_nontemporal_load(ea1 + j);
            }
        }
        const int o = valid ? (int)((unsigned)d / (unsigned)perB) : -1;
#pragma unroll
        for (int ob = 0; ob < 8; ++ob) {
            unsigned long long m = __ballot(o == ob);
            if (m == 0ull) continue;
            const int n = __popcll(m);
            const int leader = (int)(__ffsll((long long)m) - 1);
            int pos = 0;
            if (lane == leader) pos = atomicAdd(&cur8[ob], n);   // LDS atomic (fast)
            pos = __shfl(pos, leader, 64);
            if (o == ob) {
                const int rank = __popcll(m & lmask);
                const int slot = pos + rank;
                t_se[slot] = make_int2(s, __float_as_int(e));
                t_d[slot] = d;
            }
        }
    }
}

// ---------------- pass 2: within-bucket scatter (bucket = blockIdx&7 ~ XCD) ----------------
__global__ __launch_bounds__(256) void scatter_bucket_kernel(
    const int2* __restrict__ t_se, const int* __restrict__ t_d,
    const int* __restrict__ offsets, int NTd, int perB,
    int* __restrict__ cursor, int2* __restrict__ meta)
{
    const int o = blockIdx.x & 7;
    const int seg = blockIdx.x >> 3;
    const int nseg = gridDim.x >> 3;
    int dlo = o * perB; if (dlo > NTd) dlo = NTd;
    int dhi = (o + 1) * perB; if (dhi > NTd) dhi = NTd;
    const int b0 = offsets[dlo], b1 = offsets[dhi];
    const int nE = b1 - b0;
    const int e0 = b0 + (int)((long)nE * seg / nseg);
    const int e1 = b0 + (int)((long)nE * (seg + 1) / nseg);
    const int* sei = (const int*)t_se;
    for (int i = e0 + threadIdx.x; i < e1; i += 256) {
        int sx = __builtin_nontemporal_load(sei + 2 * (size_t)i);
        int sy = __builtin_nontemporal_load(sei + 2 * (size_t)i + 1);
        int d  = __builtin_nontemporal_load(t_d + i);
        int p = atomicAdd(&cursor[d], 1);
        meta[p] = make_int2(sx, sy);
    }
}

// ---------------- single-pass XCD-partitioned scatter (fallback) ----------------
__device__ __forceinline__ void scat_sub(
    const int* __restrict__ src, const int* __restrict__ dst,
    const float* __restrict__ ea, long lo, long hi,
    int dstOff, int srcOff, int dlo, int dhi,
    int* __restrict__ cursor, int2* __restrict__ meta, int tid)
{
    for (long i = lo + tid; i < hi; i += 256) {
        int d = dstOff + __builtin_nontemporal_load(dst + i);
        if (d >= dlo && d < dhi) {
            int s = __builtin_nontemporal_load(src + i) + srcOff;
            float e = __builtin_nontemporal_load(ea + i);
            int p = atomicAdd(&cursor[d], 1);
            meta[p] = make_int2(s, __float_as_int(e));
        }
    }
}

__global__ __launch_bounds__(256) void scatter_part_kernel(
    const int* __restrict__ src0, const int* __restrict__ dst0,
    const float* __restrict__ ea0, int E0,
    const int* __restrict__ src1, const int* __restrict__ dst1,
    const float* __restrict__ ea1, int E1n,
    int dstOff1, int srcOff1, int NTd,
    int* __restrict__ cursor, int2* __restrict__ meta)
{
    const int grp = blockIdx.x & 7;
    const int seg = blockIdx.x >> 3;
    const int nseg = gridDim.x >> 3;
    const int per = (NTd + 7) >> 3;
    const int dlo = grp * per;
    int dhi = dlo + per; if (dhi > NTd) dhi = NTd;
    if (dlo >= dhi) return;
    const long ET = (long)E0 + E1n;
    const long e0 = (ET * seg) / nseg;
    const long e1 = (ET * (seg + 1)) / nseg;
    const int tid = threadIdx.x;
    long a0 = e0, a1 = (e1 < E0) ? e1 : E0;
    if (a0 < a1) scat_sub(src0, dst0, ea0, a0, a1, 0, 0, dlo, dhi, cursor, meta, tid);
    long b0 = (e0 > E0) ? e0 : E0, b1 = e1;
    if (b0 < b1) scat_sub(src1, dst1, ea1, b0 - E0, b1 - E0, dstOff1, srcOff1,
                          dlo, dhi, cursor, meta, tid);
}

// ---------------- deep-pipelined streaming aggregate ----------------
struct RelP {
    const float* We; const float* be;
    const int* batch;
    float* psum;
    int Ndst;
    int offBase;
    int kskBase;
};

__global__ __launch_bounds__(256) void aggregate_v4(
    RelP P0, RelP P1, const unsigned* __restrict__ qvp,
    const unsigned* __restrict__ kskp,
    const int* __restrict__ offsets, const int2* __restrict__ meta,
    int nChunk0, int chunkHi)
{
    const int lane = threadIdx.x & 63;
    const int cid = blockIdx.x * (blockDim.x >> 6) + (threadIdx.x >> 6);
    if (cid >= chunkHi) return;
    const bool r1v = (cid >= nChunk0);
    const RelP P = r1v ? P1 : P0;
    const int dLo = (r1v ? cid - nChunk0 : cid) * DPW;
    if (dLo >= P.Ndst) return;
    const int ndst = (P.Ndst - dLo < DPW) ? (P.Ndst - dLo) : DPW;

    const float weh = P.We[lane], beh = P.be[lane];

    const int* ob = offsets + P.offBase + dLo;
    const int* bb_ = P.batch + dLo;
    int of0, of1, of2, of3, of4, of5, of6, of7, of8;
    int bg0, bg1, bg2, bg3, bg4, bg5, bg6, bg7;
#define LDO(I) __builtin_amdgcn_readfirstlane(ob[(I) < ndst ? (I) : ndst])
#define LDB(I) __builtin_amdgcn_readfirstlane(bb_[(I) < ndst ? (I) : (ndst - 1)])
    of0 = LDO(0); of1 = LDO(1); of2 = LDO(2); of3 = LDO(3); of4 = LDO(4);
    of5 = LDO(5); of6 = LDO(6); of7 = LDO(7); of8 = LDO(8);
    bg0 = LDB(0); bg1 = LDB(1); bg2 = LDB(2); bg3 = LDB(3);
    bg4 = LDB(4); bg5 = LDB(5); bg6 = LDB(6); bg7 = LDB(7);
#undef LDO
#undef LDB

    const unsigned* kb = kskp + (size_t)(P.kskBase + dLo) * H + lane;
    unsigned kp0 = kb[0], kp1 = 0, kp2 = 0, kp3 = 0, kp4 = 0, kp5 = 0, kp6 = 0, kp7 = 0;
    if (ndst > 1) kp1 = kb[1 * H];
    if (ndst > 2) kp2 = kb[2 * H];
    if (ndst > 3) kp3 = kb[3 * H];
    if (ndst > 4) kp4 = kb[4 * H];
    if (ndst > 5) kp5 = kb[5 * H];
    if (ndst > 6) kp6 = kb[6 * H];
    if (ndst > 7) kp7 = kb[7 * H];

    int idx = 0;
    float kcur = __uint_as_float(kp0 << 16);
    float skcur = __uint_as_float(kp0 & 0xffff0000u);
    int pend = of1;
    int bgcur = bg0;
    float acc = 0.f;
    const int base = of0;
    const int pstop = of8;
    const int nedges = pstop - base;
    const int ngroups = (nedges + 7) >> 3;

#define ADVANCE()                                                              \
    {                                                                          \
        float hv = fmaxf(acc + skcur, 0.f);                                    \
        atomicAdd(&P.psum[(size_t)bgcur * H + lane], hv);                      \
        ++idx;                                                                 \
        unsigned kv = sel8u(kp0, kp1, kp2, kp3, kp4, kp5, kp6, kp7, idx);      \
        kcur = __uint_as_float(kv << 16);                                      \
        skcur = __uint_as_float(kv & 0xffff0000u);                             \
        pend = sel8i(of1, of2, of3, of4, of5, of6, of7, of8, idx);             \
        bgcur = sel8i(bg0, bg1, bg2, bg3, bg4, bg5, bg6, bg7, idx);            \
        acc = 0.f;                                                             \
    }

#define ISSUE(RING, M, L8, GI)                                                 \
    if ((GI) < ngroups) {                                                      \
        _Pragma("unroll")                                                      \
        for (int j = 0; j < 8; ++j) {                                          \
            int s_ = __builtin_amdgcn_readlane((M).x, (L8) + j);               \
            RING[j] = qvp[(size_t)(unsigned)s_ * H + lane];                    \
        }                                                                      \
    }

#define CONSUME(RING, L8, GI)                                                  \
    if ((GI) < ngroups) {                                                      \
        const int e0 = (GI) * 8;                                               \
        int n_ = nedges - e0; if (n_ > 8) n_ = 8;                              \
        _Pragma("unroll")                                                      \
        for (int j = 0; j < 8; ++j) {                                          \
            if (j < n_) {                                                      \
                while (base + e0 + j >= pend) ADVANCE();                       \
                float e = fmaf(__int_as_float(                                 \
                    __builtin_amdgcn_readlane(Mc.y, (L8) + j)), weh, beh);     \
                float qq = __uint_as_float(RING[j] << 16);                     \
                float vv = __uint_as_float(RING[j] & 0xffff0000u);             \
                float g2 = fmaf(TWO_L2E, e, kcur + qq);                        \
                float sg = __builtin_amdgcn_rcpf(1.0f + __builtin_amdgcn_exp2f(-g2)); \
                acc = fmaf(sg, vv + e, acc);                                   \
            }                                                                  \
        }                                                                      \
    }

    if (nedges > 0) {
        int pos0 = base + lane; if (pos0 > pstop - 1) pos0 = pstop - 1;
        int2 Mc = meta[pos0];
        int2 Mn = Mc;
        if (nedges > 64) {
            int pos1 = base + 64 + lane; if (pos1 > pstop - 1) pos1 = pstop - 1;
            Mn = meta[pos1];
        }
        unsigned r0[8], r1[8], r2[8], r3[8];
        ISSUE(r0, Mc, 0, 0);
        ISSUE(r1, Mc, 8, 1);
        const int nsb = (ngroups + 7) >> 3;
        int sbg = 0;
        for (int sbi = 0; sbi < nsb; ++sbi, sbg += 8) {
            ISSUE(r2, Mc, 16, sbg + 2); CONSUME(r0, 0,  sbg + 0);
            ISSUE(r3, Mc, 24, sbg + 3); CONSUME(r1, 8,  sbg + 1);
            ISSUE(r0, Mc, 32, sbg + 4); CONSUME(r2, 16, sbg + 2);
            ISSUE(r1, Mc, 40, sbg + 5); CONSUME(r3, 24, sbg + 3);
            ISSUE(r2, Mc, 48, sbg + 6); CONSUME(r0, 32, sbg + 4);
            ISSUE(r3, Mc, 56, sbg + 7); CONSUME(r1, 40, sbg + 5);
            ISSUE(r0, Mn, 0,  sbg + 8); CONSUME(r2, 48, sbg + 6);
            ISSUE(r1, Mn, 8,  sbg + 9); CONSUME(r3, 56, sbg + 7);
            Mc = Mn;
            if ((sbi + 2) * 64 < nedges) {
                int pos = base + (sbi + 2) * 64 + lane;
                if (pos > pstop - 1) pos = pstop - 1;
                Mn = meta[pos];
            }
        }
    }
#undef ISSUE
#undef CONSUME

    for (;;) {
        float hv = fmaxf(acc + skcur, 0.f);
        atomicAdd(&P.psum[(size_t)bgcur * H + lane], hv);
        ++idx;
        if (idx >= ndst) break;
        unsigned kv = sel8u(kp0, kp1, kp2, kp3, kp4, kp5, kp6, kp7, idx);
        kcur = __uint_as_float(kv << 16);
        skcur = __uint_as_float(kv & 0xffff0000u);
        bgcur = sel8i(bg0, bg1, bg2, bg3, bg4, bg5, bg6, bg7, idx);
        acc = 0.f;
    }
#undef ADVANCE
}

// ---------------- MLP with fused per-graph counts ----------------
__global__ __launch_bounds__(64) void mlp_kernel(
    const float* __restrict__ sum_c, const float* __restrict__ sum_b,
    const int* __restrict__ batch_c, int Nc,
    const int* __restrict__ batch_b, int Nb,
    const float* __restrict__ W1, const float* __restrict__ b1,
    const float* __restrict__ W2, const float* __restrict__ b2,
    const float* __restrict__ W3, const float* __restrict__ b3,
    const float* __restrict__ Wout, const float* __restrict__ bout,
    float* __restrict__ out)
{
    const int g = blockIdx.x;
    const int h = threadIdx.x;
    __shared__ float pld[2 * H];
    __shared__ float hbuf[H];
    __shared__ float cnts[2];
    if (h < 2) {
        const int* a = h ? batch_b : batch_c;
        const int n = h ? Nb : Nc;
        int lo = lower_bound_i(a, n, g);
        int hi = lower_bound_i(a, n, g + 1);
        cnts[h] = fmaxf((float)(hi - lo), 1.f);
    }
    __syncthreads();
    pld[h] = sum_c[g * H + h] / cnts[0];
    pld[H + h] = sum_b[g * H + h] / cnts[1];
    __syncthreads();
    float a1 = b1[h];
    for (int j = 0; j < 2 * H; ++j) a1 = fmaf(pld[j], W1[j * H + h], a1);
    a1 = fmaxf(a1, 0.f);
    __syncthreads();
    hbuf[h] = a1;
    __syncthreads();
    float a2 = b2[h];
    for (int j = 0; j < H; ++j) a2 = fmaf(hbuf[j], W2[j * H + h], a2);
    a2 = fmaxf(a2, 0.f);
    __syncthreads();
    hbuf[h] = a2;
    __syncthreads();
    float a3 = b3[h];
    for (int j = 0; j < H; ++j) a3 = fmaf(hbuf[j], W3[j * H + h], a3);
    a3 = fmaxf(a3, 0.f);
    float p = a3 * Wout[h];
#pragma unroll
    for (int off = 32; off > 0; off >>= 1) p += __shfl_down(p, off, 64);
    if (h == 0) out[g] = p + bout[0];
}

extern "C" void kernel_launch(void* const* d_in, const int* in_sizes, int n_in,
                              void* d_out, int out_size, void* d_ws, size_t ws_size,
                              hipStream_t stream) {
    const float* x_x   = (const float*)d_in[0];
    const float* x_c   = (const float*)d_in[1];
    const float* x_b   = (const float*)d_in[2];
    const float* ea_ac = (const float*)d_in[3];
    const float* ea_cb = (const float*)d_in[4];

    const float* Wk_ac = (const float*)d_in[5];
    const float* Wq_ac = (const float*)d_in[6];
    const float* Wv_ac = (const float*)d_in[7];
    const float* Wskip_ac = (const float*)d_in[8];
    const float* We_ac = (const float*)d_in[9];
    const float* bk_ac = (const float*)d_in[10];
    const float* bq_ac = (const float*)d_in[11];
    const float* bv_ac = (const float*)d_in[12];
    const float* be_ac = (const float*)d_in[13];
    const float* bconv_ac = (const float*)d_in[14];

    const float* Wk_cb = (const float*)d_in[15];
    const float* Wq_cb = (const float*)d_in[16];
    const float* Wv_cb = (const float*)d_in[17];
    const float* Wskip_cb = (const float*)d_in[18];
    const float* We_cb = (const float*)d_in[19];
    const float* bk_cb = (const float*)d_in[20];
    const float* bq_cb = (const float*)d_in[21];
    const float* bv_cb = (const float*)d_in[22];
    const float* be_cb = (const float*)d_in[23];
    const float* bconv_cb = (const float*)d_in[24];

    const float* W1 = (const float*)d_in[25];
    const float* b1 = (const float*)d_in[26];
    const float* W2 = (const float*)d_in[27];
    const float* b2 = (const float*)d_in[28];
    const float* W3 = (const float*)d_in[29];
    const float* b3 = (const float*)d_in[30];
    const float* Wout = (const float*)d_in[31];
    const float* bout = (const float*)d_in[32];

    const int* src_ac = (const int*)d_in[33];
    const int* dst_ac = (const int*)d_in[34];
    const int* src_cb = (const int*)d_in[35];
    const int* dst_cb = (const int*)d_in[36];
    const int* batch_c = (const int*)d_in[37];
    const int* batch_b = (const int*)d_in[38];

    const int Nx = in_sizes[0] / F;
    const int Nc = in_sizes[1] / F;
    const int Nb = in_sizes[2] / F;
    const int E1 = in_sizes[33];
    const int E2 = in_sizes[35];
    (void)n_in; (void)out_size;

    const int NT = Nc + Nb;
    const size_t ET = (size_t)E1 + E2;
    const int NMAX = (Nc > Nb ? Nc : Nb);
    const int EMAX = (E1 > E2 ? E1 : E2);
    const int SRCMAX = (Nx > Nc ? Nx : Nc);
    const size_t SUMS = 2 * NUM_G * H;

    const size_t wordsA = 2 * ET + (size_t)(NT + 1) + NT + 256 + SUMS
                        + (size_t)(Nx + Nc) * H + (size_t)(Nc + Nb) * H;
    const size_t wordsA2 = wordsA + 3 * ET + 8 * NBLK;   // + staging + block hist
    const bool pathA  = (ws_size >= wordsA * 4);
    const bool pathA2 = (ws_size >= wordsA2 * 4);

    int* ws = (int*)d_ws;
    const size_t metaN = pathA ? 2 * ET : 2 * (size_t)EMAX;
    const int nOff = pathA ? NT : NMAX;
    int2*     meta    = (int2*)ws;
    int*      offsets = ws + metaN;
    int*      cnt     = offsets + (nOff + 1);
    int*      bsums   = cnt + nOff;
    float*    sum_c   = (float*)(bsums + 256);
    float*    sum_b   = sum_c + NUM_G * H;
    unsigned* qvp     = (unsigned*)(sum_b + NUM_G * H);
    unsigned* kskp    = qvp + (size_t)(pathA ? (Nx + Nc) : SRCMAX) * H;
    int2*     t_se    = (int2*)(kskp + (size_t)(pathA ? (Nc + Nb) : NMAX) * H);
    int*      t_d     = (int*)(t_se + ET);
    int*      bhist   = t_d + ET;

    const int nC0 = (Nc + DPW - 1) / DPW;
    const int nC1 = (Nb + DPW - 1) / DPW;

    RelP P0, P1;
    P0.We = We_ac; P0.be = be_ac; P0.batch = batch_c; P0.psum = sum_c;
    P0.Ndst = Nc; P0.offBase = 0; P0.kskBase = 0;
    P1.We = We_cb; P1.be = be_cb; P1.batch = batch_b; P1.psum = sum_b;
    P1.Ndst = Nb; P1.offBase = pathA ? Nc : 0; P1.kskBase = pathA ? Nc : 0;

    if (pathA) {
        // one memset covers cnt | bsums | sum_c | sum_b (contiguous)
        hipMemsetAsync(cnt, 0, (size_t)(NT + 256 + SUMS) * sizeof(int), stream);

        const int nScan = (NT + 2047) / 2048;
        const int EB = (int)((ET + 255) / 256);
        const int w1 = (Nx + PROJ_ROWS - 1) / PROJ_ROWS;
        const int w2 = w1 + (Nc + PROJ_ROWS - 1) / PROJ_ROWS;
        const int w3 = w2 + (Nc + PROJ_ROWS - 1) / PROJ_ROWS;
        const int wTot = w3 + (Nb + PROJ_ROWS - 1) / PROJ_ROWS;
        ProjSec s0 = { x_x, Wq_ac, bq_ac, Wv_ac, bv_ac, qvp, Nx, 0, L2E };
        ProjSec s1 = { x_c, Wq_cb, bq_cb, Wv_cb, bv_cb, qvp + (size_t)Nx * H, Nc, w1, L2E };
        ProjSec s2 = { x_c, Wk_ac, bk_ac, Wskip_ac, bconv_ac, kskp, Nc, w2, L2E };
        ProjSec s3 = { x_b, Wk_cb, bk_cb, Wskip_cb, bconv_cb, kskp + (size_t)Nc * H, Nb, w3, L2E };
        const int projB = (wTot + 3) / 4;

        hist_proj_kernel<<<EB + projB, 256, 0, stream>>>(
            dst_ac, E1, dst_cb, E2, Nc, cnt, EB, s0, s1, s2, s3, wTot);
        scan_partial<<<nScan, 256, 0, stream>>>(cnt, bsums, NT);
        scan_bsums<<<1, 256, 0, stream>>>(bsums, nScan);
        scan_final<<<nScan, 256, 0, stream>>>(cnt, bsums, offsets, NT);

        const int perB = (NT + 7) / 8;
        if (pathA2) {
            bhist_kernel<<<NBLK, 256, 0, stream>>>(dst_ac, E1, dst_cb, E2, Nc, perB, bhist);
            bscan_kernel<<<1, 512, 0, stream>>>(bhist);
            bscatter_kernel<<<NBLK, 256, 0, stream>>>(
                src_ac, dst_ac, ea_ac, E1, src_cb, dst_cb, ea_cb, E2,
                Nc, Nx, NT, perB, offsets, bhist, t_se, t_d);
            scatter_bucket_kernel<<<2048, 256, 0, stream>>>(
                t_se, t_d, offsets, NT, perB, cnt, meta);
        } else {
            scatter_part_kernel<<<2048, 256, 0, stream>>>(
                src_ac, dst_ac, ea_ac, E1, src_cb, dst_cb, ea_cb, E2,
                Nc, Nx, NT, cnt, meta);
        }

        const int nW = nC0 + nC1;
        aggregate_v4<<<(nW + 3) / 4, 256, 0, stream>>>(
            P0, P1, qvp, kskp, offsets, meta, nC0, nW);
    } else {
        hipMemsetAsync(sum_c, 0, SUMS * sizeof(float), stream);
        for (int rel = 0; rel < 2; ++rel) {
            const int n = rel ? Nb : Nc;
            const int E = rel ? E2 : E1;
            const int Ns = rel ? Nc : Nx;
            const int* srcA = rel ? src_cb : src_ac;
            const int* dstA = rel ? dst_cb : dst_ac;
            const float* eaA = rel ? ea_cb : ea_ac;
            const float* xs = rel ? x_c : x_x;
            const float* xd = rel ? x_b : x_c;
            const float* Wq = rel ? Wq_cb : Wq_ac; const float* bq = rel ? bq_cb : bq_ac;
            const float* Wv = rel ? Wv_cb : Wv_ac; const float* bv = rel ? bv_cb : bv_ac;
            const float* Wk = rel ? Wk_cb : Wk_ac; const float* bk = rel ? bk_cb : bk_ac;
            const float* Wsk = rel ? Wskip_cb : Wskip_ac;
            const float* bcv = rel ? bconv_cb : bconv_ac;
            const int nScan = (n + 2047) / 2048;
            hipMemsetAsync(cnt, 0, n * sizeof(int), stream);
            const int w1 = (Ns + PROJ_ROWS - 1) / PROJ_ROWS;
            const int wTot = w1 + (n + PROJ_ROWS - 1) / PROJ_ROWS;
            ProjSec s0 = { xs, Wq, bq, Wv, bv, qvp, Ns, 0, L2E };
            ProjSec s1 = { xs, Wq, bq, Wv, bv, qvp, 0, w1, L2E };
            ProjSec s2 = { xd, Wk, bk, Wsk, bcv, kskp, n, w1, L2E };
            ProjSec s3 = { xd, Wk, bk, Wsk, bcv, kskp, 0, wTot, L2E };
            const int EB = (E + 255) / 256;
            const int projB = (wTot + 3) / 4;
            hist_proj_kernel<<<EB + projB, 256, 0, stream>>>(
                dstA, E, dstA, 0, 0, cnt, EB, s0, s1, s2, s3, wTot);
            scan_partial<<<nScan, 256, 0, stream>>>(cnt, bsums, n);
            scan_bsums<<<1, 256, 0, stream>>>(bsums, nScan);
            scan_final<<<nScan, 256, 0, stream>>>(cnt, bsums, offsets, n);
            scatter_part_kernel<<<2048, 256, 0, stream>>>(
                srcA, dstA, eaA, E, srcA, dstA, eaA, 0, 0, 0, n, cnt, meta);
            RelP PR = rel ? P1 : P0;
            const int nCr = rel ? nC1 : nC0;
            aggregate_v4<<<(nCr + 3) / 4, 256, 0, stream>>>(
                PR, PR, qvp, kskp, offsets, meta, nCr, nCr);
        }
    }

    mlp_kernel<<<NUM_G, 64, 0, stream>>>(
        sum_c, sum_b, batch_c, Nc, batch_b, Nb,
        W1, b1, W2, b2, W3, b3, Wout, bout, (float*)d_out);
}

// Round 11
// 496.074 us; speedup vs baseline: 6.1728x; 1.3962x over previous
//
#include <hip/hip_runtime.h>
#include <math.h>

#define H 64
#define F 16
#define NUM_G 128
#define DPW 8
#define NBLK 512     // segments for bucket partition
#define SORTB 256    // dst-range buckets (= one sort block per CU)
#define L2E 1.4426950408889634f
#define TWO_L2E 2.8853900817779268f

__device__ __forceinline__ int lower_bound_i(const int* a, int n, int key) {
    int lo = 0, hi = n;
    while (lo < hi) { int mid = (lo + hi) >> 1; if (a[mid] < key) lo = mid + 1; else hi = mid; }
    return lo;
}

__device__ __forceinline__ unsigned bf16rne(float f) {
    unsigned u = __float_as_uint(f);
    return (u + 0x7fffu + ((u >> 16) & 1u)) >> 16;
}

__device__ __forceinline__ unsigned sel8u(unsigned a0, unsigned a1, unsigned a2, unsigned a3,
                                          unsigned a4, unsigned a5, unsigned a6, unsigned a7, int i) {
    unsigned b0 = (i & 1) ? a1 : a0, b1 = (i & 1) ? a3 : a2;
    unsigned b2 = (i & 1) ? a5 : a4, b3 = (i & 1) ? a7 : a6;
    unsigned c0 = (i & 2) ? b1 : b0, c1 = (i & 2) ? b3 : b2;
    return (i & 4) ? c1 : c0;
}
__device__ __forceinline__ int sel8i(int a0, int a1, int a2, int a3,
                                     int a4, int a5, int a6, int a7, int i) {
    int b0 = (i & 1) ? a1 : a0, b1 = (i & 1) ? a3 : a2;
    int b2 = (i & 1) ? a5 : a4, b3 = (i & 1) ? a7 : a6;
    int c0 = (i & 2) ? b1 : b0, c1 = (i & 2) ? b3 : b2;
    return (i & 4) ? c1 : c0;
}

// ---------------- projection section descriptor ----------------
struct ProjSec {
    const float* x; const float* Wa; const float* ba;
    const float* Wb; const float* bb2; unsigned* out;
    int N; int waveOff; float scaleA;
};
#define PROJ_ROWS 16

// ---------------- fused (optional histogram) + projections ----------------
__global__ __launch_bounds__(256) void hist_proj_kernel(
    const int* __restrict__ dst0, int E0,
    const int* __restrict__ dst1, int E1n, int dstOff1,
    int* __restrict__ cnt, int histBlocks,
    ProjSec s0, ProjSec s1, ProjSec s2, ProjSec s3, int wTot)
{
    if ((int)blockIdx.x < histBlocks) {
        int i = blockIdx.x * blockDim.x + threadIdx.x;
        if (i < E0) {
            atomicAdd(&cnt[dst0[i]], 1);
        } else {
            i -= E0;
            if (i < E1n) atomicAdd(&cnt[dstOff1 + dst1[i]], 1);
        }
        return;
    }
    const int lane = threadIdx.x & 63;
    const int w = (blockIdx.x - histBlocks) * (blockDim.x >> 6) + (threadIdx.x >> 6);
    if (w >= wTot) return;
    ProjSec S = (w >= s3.waveOff) ? s3 : (w >= s2.waveOff) ? s2 : (w >= s1.waveOff) ? s1 : s0;
    const int r0 = (w - S.waveOff) * PROJ_ROWS;
    float wa[F], wb[F];
#pragma unroll
    for (int f = 0; f < F; ++f) {
        wa[f] = S.Wa[f * H + lane] * S.scaleA;
        wb[f] = S.Wb[f * H + lane];
    }
    const float bah = S.ba[lane] * S.scaleA, bbh = S.bb2[lane];
    int r1e = r0 + PROJ_ROWS; if (r1e > S.N) r1e = S.N;
    for (int n = r0; n < r1e; ++n) {
        const float4* xr = (const float4*)(S.x + (size_t)n * F);
        float a = bah, b = bbh;
#pragma unroll
        for (int f4 = 0; f4 < F / 4; ++f4) {
            float4 t = xr[f4];
            a = fmaf(t.x, wa[4*f4+0], a); a = fmaf(t.y, wa[4*f4+1], a);
            a = fmaf(t.z, wa[4*f4+2], a); a = fmaf(t.w, wa[4*f4+3], a);
            b = fmaf(t.x, wb[4*f4+0], b); b = fmaf(t.y, wb[4*f4+1], b);
            b = fmaf(t.z, wb[4*f4+2], b); b = fmaf(t.w, wb[4*f4+3], b);
        }
        S.out[(size_t)n * H + lane] = bf16rne(a) | (bf16rne(b) << 16);
    }
}

// ---------------- fallback global scan (pathA / per-rel only) ----------------
__global__ __launch_bounds__(256) void scan_partial(const int* __restrict__ cnt,
                                                    int* __restrict__ bsums, int n) {
    __shared__ int red[256];
    const int b = blockIdx.x, t = threadIdx.x;
    const int base = b * 2048 + t * 8;
    int s = 0;
#pragma unroll
    for (int i = 0; i < 8; ++i) { int idx = base + i; if (idx < n) s += cnt[idx]; }
    red[t] = s;
    __syncthreads();
    for (int off = 128; off > 0; off >>= 1) {
        if (t < off) red[t] += red[t + off];
        __syncthreads();
    }
    if (t == 0) bsums[b] = red[0];
}

__global__ __launch_bounds__(256) void scan_bsums(int* __restrict__ bsums, int nb) {
    __shared__ int sh[256];
    const int t = threadIdx.x;
    sh[t] = (t < nb) ? bsums[t] : 0;
    __syncthreads();
    for (int off = 1; off < 256; off <<= 1) {
        int v = sh[t];
        int add = (t >= off) ? sh[t - off] : 0;
        __syncthreads();
        sh[t] = v + add;
        __syncthreads();
    }
    if (t < nb) bsums[t] = (t == 0) ? 0 : sh[t - 1];
}

__global__ __launch_bounds__(256) void scan_final(int* __restrict__ cnt,
                                                  const int* __restrict__ bsums,
                                                  int* __restrict__ offsets, int n) {
    __shared__ int red[256];
    const int b = blockIdx.x, t = threadIdx.x;
    const int base = b * 2048 + t * 8;
    int v[8]; int s = 0;
#pragma unroll
    for (int i = 0; i < 8; ++i) { int idx = base + i; v[i] = (idx < n) ? cnt[idx] : 0; s += v[i]; }
    red[t] = s;
    __syncthreads();
    for (int off = 1; off < 256; off <<= 1) {
        int val = red[t];
        int add = (t >= off) ? red[t - off] : 0;
        __syncthreads();
        red[t] = val + add;
        __syncthreads();
    }
    const int ex = (t == 0) ? 0 : red[t - 1];
    int run = bsums[b] + ex;
#pragma unroll
    for (int i = 0; i < 8; ++i) {
        int idx = base + i;
        if (idx < n) { offsets[idx] = run; cnt[idx] = run; }
        run += v[i];
    }
    if (t == 255 && b == gridDim.x - 1) offsets[n] = run;
}

// ---------------- bucket pipeline 1: per-segment bucket histogram (LDS) ----------------
__global__ __launch_bounds__(256) void bhist_kernel(
    const int* __restrict__ dst0, int E0,
    const int* __restrict__ dst1, int E1n,
    int dstOff1, int perB, int* __restrict__ bhist)
{
    __shared__ int c[SORTB];
    if (threadIdx.x < SORTB) c[threadIdx.x] = 0;
    __syncthreads();
    const long ET = (long)E0 + E1n;
    const long e0 = ET * blockIdx.x / NBLK;
    const long e1 = ET * (blockIdx.x + 1) / NBLK;
    for (long i = e0 + threadIdx.x; i < e1; i += 256) {
        int d = (i < E0) ? __builtin_nontemporal_load(dst0 + i)
                         : dstOff1 + __builtin_nontemporal_load(dst1 + (i - E0));
        atomicAdd(&c[(unsigned)d / (unsigned)perB], 1);
    }
    __syncthreads();
    if (threadIdx.x < SORTB) bhist[threadIdx.x * NBLK + blockIdx.x] = c[threadIdx.x];
}

// ---------------- bucket pipeline 2: bucket totals exclusive scan ----------------
__global__ __launch_bounds__(256) void btot_scan_kernel(const int* __restrict__ bhist,
                                                        int* __restrict__ bucketStart)
{
    const int t = threadIdx.x;
    int s = 0;
    for (int b = 0; b < NBLK; ++b) s += bhist[t * NBLK + b];
    __shared__ int part[256];
    part[t] = s;
    __syncthreads();
    for (int off = 1; off < 256; off <<= 1) {
        int v = part[t];
        int add = (t >= off) ? part[t - off] : 0;
        __syncthreads();
        part[t] = v + add;
        __syncthreads();
    }
    int excl = (t == 0) ? 0 : part[t - 1];
    bucketStart[t] = excl;
    if (t == 255) bucketStart[256] = excl + s;
}

// ---------------- bucket pipeline 3: per-bucket scan over blocks ----------------
__global__ __launch_bounds__(256) void bhist_scan_kernel(int* __restrict__ bhist,
                                                         const int* __restrict__ bucketStart)
{
    const int o = blockIdx.x, t = threadIdx.x;
    int v0 = bhist[o * NBLK + 2 * t];
    int v1 = bhist[o * NBLK + 2 * t + 1];
    __shared__ int part[256];
    part[t] = v0 + v1;
    __syncthreads();
    for (int off = 1; off < 256; off <<= 1) {
        int v = part[t];
        int add = (t >= off) ? part[t - off] : 0;
        __syncthreads();
        part[t] = v + add;
        __syncthreads();
    }
    int excl = (t == 0) ? 0 : part[t - 1];
    const int base = bucketStart[o];
    bhist[o * NBLK + 2 * t] = base + excl;
    bhist[o * NBLK + 2 * t + 1] = base + excl + v0;
}

// ---------------- bucket pipeline 4: deterministic bucket partition ----------------
__global__ __launch_bounds__(256) void bscatter_kernel(
    const int* __restrict__ src0, const int* __restrict__ dst0,
    const float* __restrict__ ea0, int E0,
    const int* __restrict__ src1, const int* __restrict__ dst1,
    const float* __restrict__ ea1, int E1n,
    int dstOff1, int srcOff1, int perB,
    const int* __restrict__ bhist,
    int2* __restrict__ t_se, int* __restrict__ t_d)
{
    __shared__ int cur[SORTB];
    if (threadIdx.x < SORTB)
        cur[threadIdx.x] = bhist[threadIdx.x * NBLK + blockIdx.x];
    __syncthreads();
    const long ET = (long)E0 + E1n;
    const long e0 = ET * blockIdx.x / NBLK;
    const long e1 = ET * (blockIdx.x + 1) / NBLK;
    for (long i = e0 + threadIdx.x; i < e1; i += 256) {
        int s, d; float e;
        if (i < E0) {
            s = __builtin_nontemporal_load(src0 + i);
            d = __builtin_nontemporal_load(dst0 + i);
            e = __builtin_nontemporal_load(ea0 + i);
        } else {
            long j = i - E0;
            s = __builtin_nontemporal_load(src1 + j) + srcOff1;
            d = __builtin_nontemporal_load(dst1 + j) + dstOff1;
            e = __builtin_nontemporal_load(ea1 + j);
        }
        int o = (unsigned)d / (unsigned)perB;
        int slot = atomicAdd(&cur[o], 1);     // LDS atomic
        t_se[slot] = make_int2(s, __float_as_int(e));
        t_d[slot] = d;
    }
}

// ---------------- bucket pipeline 5: per-bucket LDS sort -> offsets + meta ----------------
__global__ __launch_bounds__(256) void bucket_sort_kernel(
    const int2* __restrict__ t_se, const int* __restrict__ t_d,
    const int* __restrict__ bucketStart, int NT, int perB,
    int* __restrict__ offsets, int2* __restrict__ meta)
{
    extern __shared__ int lds[];     // cnt[perB] | part[256]
    int* cnt = lds;
    int* part = lds + perB;
    const int o = blockIdx.x, t = threadIdx.x;
    int dlo = o * perB; if (dlo > NT) dlo = NT;
    int dhi = dlo + perB; if (dhi > NT) dhi = NT;
    const int nd = dhi - dlo;
    for (int i = t; i < nd; i += 256) cnt[i] = 0;
    __syncthreads();
    const int b0 = bucketStart[o], b1 = bucketStart[o + 1];
    for (int i = b0 + t; i < b1; i += 256)
        atomicAdd(&cnt[t_d[i] - dlo], 1);
    __syncthreads();
    // exclusive scan of cnt[0..nd)
    const int C = (nd + 255) / 256;
    const int lo = t * C;
    int hi = lo + C; if (hi > nd) hi = nd;
    int s = 0;
    for (int j = lo; j < hi; ++j) s += cnt[j];
    part[t] = s;
    __syncthreads();
    for (int off = 1; off < 256; off <<= 1) {
        int v = part[t];
        int add = (t >= off) ? part[t - off] : 0;
        __syncthreads();
        part[t] = v + add;
        __syncthreads();
    }
    int run = (t == 0) ? 0 : part[t - 1];
    for (int j = lo; j < hi; ++j) { int v = cnt[j]; cnt[j] = run; run += v; }
    __syncthreads();
    for (int i = t; i < nd; i += 256) offsets[dlo + i] = b0 + cnt[i];
    if (dhi == NT && t == 0) offsets[NT] = b1;
    __syncthreads();
    for (int i = b0 + t; i < b1; i += 256) {
        int d = t_d[i];
        int2 se = t_se[i];
        int slot = b0 + atomicAdd(&cnt[d - dlo], 1);
        meta[slot] = se;
    }
}

// ---------------- single-pass XCD-partitioned scatter (fallback) ----------------
__device__ __forceinline__ void scat_sub(
    const int* __restrict__ src, const int* __restrict__ dst,
    const float* __restrict__ ea, long lo, long hi,
    int dstOff, int srcOff, int dlo, int dhi,
    int* __restrict__ cursor, int2* __restrict__ meta, int tid)
{
    for (long i = lo + tid; i < hi; i += 256) {
        int d = dstOff + __builtin_nontemporal_load(dst + i);
        if (d >= dlo && d < dhi) {
            int s = __builtin_nontemporal_load(src + i) + srcOff;
            float e = __builtin_nontemporal_load(ea + i);
            int p = atomicAdd(&cursor[d], 1);
            meta[p] = make_int2(s, __float_as_int(e));
        }
    }
}

__global__ __launch_bounds__(256) void scatter_part_kernel(
    const int* __restrict__ src0, const int* __restrict__ dst0,
    const float* __restrict__ ea0, int E0,
    const int* __restrict__ src1, const int* __restrict__ dst1,
    const float* __restrict__ ea1, int E1n,
    int dstOff1, int srcOff1, int NTd,
    int* __restrict__ cursor, int2* __restrict__ meta)
{
    const int grp = blockIdx.x & 7;
    const int seg = blockIdx.x >> 3;
    const int nseg = gridDim.x >> 3;
    const int per = (NTd + 7) >> 3;
    const int dlo = grp * per;
    int dhi = dlo + per; if (dhi > NTd) dhi = NTd;
    if (dlo >= dhi) return;
    const long ET = (long)E0 + E1n;
    const long e0 = (ET * seg) / nseg;
    const long e1 = (ET * (seg + 1)) / nseg;
    const int tid = threadIdx.x;
    long a0 = e0, a1 = (e1 < E0) ? e1 : E0;
    if (a0 < a1) scat_sub(src0, dst0, ea0, a0, a1, 0, 0, dlo, dhi, cursor, meta, tid);
    long b0 = (e0 > E0) ? e0 : E0, b1 = e1;
    if (b0 < b1) scat_sub(src1, dst1, ea1, b0 - E0, b1 - E0, dstOff1, srcOff1,
                          dlo, dhi, cursor, meta, tid);
}

// ---------------- deep-pipelined streaming aggregate ----------------
struct RelP {
    const float* We; const float* be;
    const int* batch;
    float* psum;
    int Ndst;
    int offBase;
    int kskBase;
};

__global__ __launch_bounds__(256) void aggregate_v4(
    RelP P0, RelP P1, const unsigned* __restrict__ qvp,
    const unsigned* __restrict__ kskp,
    const int* __restrict__ offsets, const int2* __restrict__ meta,
    int nChunk0, int chunkHi)
{
    const int lane = threadIdx.x & 63;
    const int cid = blockIdx.x * (blockDim.x >> 6) + (threadIdx.x >> 6);
    if (cid >= chunkHi) return;
    const bool r1v = (cid >= nChunk0);
    const RelP P = r1v ? P1 : P0;
    const int dLo = (r1v ? cid - nChunk0 : cid) * DPW;
    if (dLo >= P.Ndst) return;
    const int ndst = (P.Ndst - dLo < DPW) ? (P.Ndst - dLo) : DPW;

    const float weh = P.We[lane], beh = P.be[lane];

    const int* ob = offsets + P.offBase + dLo;
    const int* bb_ = P.batch + dLo;
    int of0, of1, of2, of3, of4, of5, of6, of7, of8;
    int bg0, bg1, bg2, bg3, bg4, bg5, bg6, bg7;
#define LDO(I) __builtin_amdgcn_readfirstlane(ob[(I) < ndst ? (I) : ndst])
#define LDB(I) __builtin_amdgcn_readfirstlane(bb_[(I) < ndst ? (I) : (ndst - 1)])
    of0 = LDO(0); of1 = LDO(1); of2 = LDO(2); of3 = LDO(3); of4 = LDO(4);
    of5 = LDO(5); of6 = LDO(6); of7 = LDO(7); of8 = LDO(8);
    bg0 = LDB(0); bg1 = LDB(1); bg2 = LDB(2); bg3 = LDB(3);
    bg4 = LDB(4); bg5 = LDB(5); bg6 = LDB(6); bg7 = LDB(7);
#undef LDO
#undef LDB

    const unsigned* kb = kskp + (size_t)(P.kskBase + dLo) * H + lane;
    unsigned kp0 = kb[0], kp1 = 0, kp2 = 0, kp3 = 0, kp4 = 0, kp5 = 0, kp6 = 0, kp7 = 0;
    if (ndst > 1) kp1 = kb[1 * H];
    if (ndst > 2) kp2 = kb[2 * H];
    if (ndst > 3) kp3 = kb[3 * H];
    if (ndst > 4) kp4 = kb[4 * H];
    if (ndst > 5) kp5 = kb[5 * H];
    if (ndst > 6) kp6 = kb[6 * H];
    if (ndst > 7) kp7 = kb[7 * H];

    int idx = 0;
    float kcur = __uint_as_float(kp0 << 16);
    float skcur = __uint_as_float(kp0 & 0xffff0000u);
    int pend = of1;
    int bgcur = bg0;
    float acc = 0.f;
    const int base = of0;
    const int pstop = of8;
    const int nedges = pstop - base;
    const int ngroups = (nedges + 7) >> 3;

#define ADVANCE()                                                              \
    {                                                                          \
        float hv = fmaxf(acc + skcur, 0.f);                                    \
        atomicAdd(&P.psum[(size_t)bgcur * H + lane], hv);                      \
        ++idx;                                                                 \
        unsigned kv = sel8u(kp0, kp1, kp2, kp3, kp4, kp5, kp6, kp7, idx);      \
        kcur = __uint_as_float(kv << 16);                                      \
        skcur = __uint_as_float(kv & 0xffff0000u);                             \
        pend = sel8i(of1, of2, of3, of4, of5, of6, of7, of8, idx);             \
        bgcur = sel8i(bg0, bg1, bg2, bg3, bg4, bg5, bg6, bg7, idx);            \
        acc = 0.f;                                                             \
    }

#define ISSUE(RING, M, L8, GI)                                                 \
    if ((GI) < ngroups) {                                                      \
        _Pragma("unroll")                                                      \
        for (int j = 0; j < 8; ++j) {                                          \
            int s_ = __builtin_amdgcn_readlane((M).x, (L8) + j);               \
            RING[j] = qvp[(size_t)(unsigned)s_ * H + lane];                    \
        }                                                                      \
    }

#define CONSUME(RING, L8, GI)                                                  \
    if ((GI) < ngroups) {                                                      \
        const int e0 = (GI) * 8;                                               \
        int n_ = nedges - e0; if (n_ > 8) n_ = 8;                              \
        _Pragma("unroll")                                                      \
        for (int j = 0; j < 8; ++j) {                                          \
            if (j < n_) {                                                      \
                while (base + e0 + j >= pend) ADVANCE();                       \
                float e = fmaf(__int_as_float(                                 \
                    __builtin_amdgcn_readlane(Mc.y, (L8) + j)), weh, beh);     \
                float qq = __uint_as_float(RING[j] << 16);                     \
                float vv = __uint_as_float(RING[j] & 0xffff0000u);             \
                float g2 = fmaf(TWO_L2E, e, kcur + qq);                        \
                float sg = __builtin_amdgcn_rcpf(1.0f + __builtin_amdgcn_exp2f(-g2)); \
                acc = fmaf(sg, vv + e, acc);                                   \
            }                                                                  \
        }                                                                      \
    }

    if (nedges > 0) {
        int pos0 = base + lane; if (pos0 > pstop - 1) pos0 = pstop - 1;
        int2 Mc = meta[pos0];
        int2 Mn = Mc;
        if (nedges > 64) {
            int pos1 = base + 64 + lane; if (pos1 > pstop - 1) pos1 = pstop - 1;
            Mn = meta[pos1];
        }
        unsigned r0[8], r1[8], r2[8], r3[8];
        ISSUE(r0, Mc, 0, 0);
        ISSUE(r1, Mc, 8, 1);
        const int nsb = (ngroups + 7) >> 3;
        int sbg = 0;
        for (int sbi = 0; sbi < nsb; ++sbi, sbg += 8) {
            ISSUE(r2, Mc, 16, sbg + 2); CONSUME(r0, 0,  sbg + 0);
            ISSUE(r3, Mc, 24, sbg + 3); CONSUME(r1, 8,  sbg + 1);
            ISSUE(r0, Mc, 32, sbg + 4); CONSUME(r2, 16, sbg + 2);
            ISSUE(r1, Mc, 40, sbg + 5); CONSUME(r3, 24, sbg + 3);
            ISSUE(r2, Mc, 48, sbg + 6); CONSUME(r0, 32, sbg + 4);
            ISSUE(r3, Mc, 56, sbg + 7); CONSUME(r1, 40, sbg + 5);
            ISSUE(r0, Mn, 0,  sbg + 8); CONSUME(r2, 48, sbg + 6);
            ISSUE(r1, Mn, 8,  sbg + 9); CONSUME(r3, 56, sbg + 7);
            Mc = Mn;
            if ((sbi + 2) * 64 < nedges) {
                int pos = base + (sbi + 2) * 64 + lane;
                if (pos > pstop - 1) pos = pstop - 1;
                Mn = meta[pos];
            }
        }
    }
#undef ISSUE
#undef CONSUME

    for (;;) {
        float hv = fmaxf(acc + skcur, 0.f);
        atomicAdd(&P.psum[(size_t)bgcur * H + lane], hv);
        ++idx;
        if (idx >= ndst) break;
        unsigned kv = sel8u(kp0, kp1, kp2, kp3, kp4, kp5, kp6, kp7, idx);
        kcur = __uint_as_float(kv << 16);
        skcur = __uint_as_float(kv & 0xffff0000u);
        bgcur = sel8i(bg0, bg1, bg2, bg3, bg4, bg5, bg6, bg7, idx);
        acc = 0.f;
    }
#undef ADVANCE
}

// ---------------- MLP with fused per-graph counts ----------------
__global__ __launch_bounds__(64) void mlp_kernel(
    const float* __restrict__ sum_c, const float* __restrict__ sum_b,
    const int* __restrict__ batch_c, int Nc,
    const int* __restrict__ batch_b, int Nb,
    const float* __restrict__ W1, const float* __restrict__ b1,
    const float* __restrict__ W2, const float* __restrict__ b2,
    const float* __restrict__ W3, const float* __restrict__ b3,
    const float* __restrict__ Wout, const float* __restrict__ bout,
    float* __restrict__ out)
{
    const int g = blockIdx.x;
    const int h = threadIdx.x;
    __shared__ float pld[2 * H];
    __shared__ float hbuf[H];
    __shared__ float cnts[2];
    if (h < 2) {
        const int* a = h ? batch_b : batch_c;
        const int n = h ? Nb : Nc;
        int lo = lower_bound_i(a, n, g);
        int hi = lower_bound_i(a, n, g + 1);
        cnts[h] = fmaxf((float)(hi - lo), 1.f);
    }
    __syncthreads();
    pld[h] = sum_c[g * H + h] / cnts[0];
    pld[H + h] = sum_b[g * H + h] / cnts[1];
    __syncthreads();
    float a1 = b1[h];
    for (int j = 0; j < 2 * H; ++j) a1 = fmaf(pld[j], W1[j * H + h], a1);
    a1 = fmaxf(a1, 0.f);
    __syncthreads();
    hbuf[h] = a1;
    __syncthreads();
    float a2 = b2[h];
    for (int j = 0; j < H; ++j) a2 = fmaf(hbuf[j], W2[j * H + h], a2);
    a2 = fmaxf(a2, 0.f);
    __syncthreads();
    hbuf[h] = a2;
    __syncthreads();
    float a3 = b3[h];
    for (int j = 0; j < H; ++j) a3 = fmaf(hbuf[j], W3[j * H + h], a3);
    a3 = fmaxf(a3, 0.f);
    float p = a3 * Wout[h];
#pragma unroll
    for (int off = 32; off > 0; off >>= 1) p += __shfl_down(p, off, 64);
    if (h == 0) out[g] = p + bout[0];
}

extern "C" void kernel_launch(void* const* d_in, const int* in_sizes, int n_in,
                              void* d_out, int out_size, void* d_ws, size_t ws_size,
                              hipStream_t stream) {
    const float* x_x   = (const float*)d_in[0];
    const float* x_c   = (const float*)d_in[1];
    const float* x_b   = (const float*)d_in[2];
    const float* ea_ac = (const float*)d_in[3];
    const float* ea_cb = (const float*)d_in[4];

    const float* Wk_ac = (const float*)d_in[5];
    const float* Wq_ac = (const float*)d_in[6];
    const float* Wv_ac = (const float*)d_in[7];
    const float* Wskip_ac = (const float*)d_in[8];
    const float* We_ac = (const float*)d_in[9];
    const float* bk_ac = (const float*)d_in[10];
    const float* bq_ac = (const float*)d_in[11];
    const float* bv_ac = (const float*)d_in[12];
    const float* be_ac = (const float*)d_in[13];
    const float* bconv_ac = (const float*)d_in[14];

    const float* Wk_cb = (const float*)d_in[15];
    const float* Wq_cb = (const float*)d_in[16];
    const float* Wv_cb = (const float*)d_in[17];
    const float* Wskip_cb = (const float*)d_in[18];
    const float* We_cb = (const float*)d_in[19];
    const float* bk_cb = (const float*)d_in[20];
    const float* bq_cb = (const float*)d_in[21];
    const float* bv_cb = (const float*)d_in[22];
    const float* be_cb = (const float*)d_in[23];
    const float* bconv_cb = (const float*)d_in[24];

    const float* W1 = (const float*)d_in[25];
    const float* b1 = (const float*)d_in[26];
    const float* W2 = (const float*)d_in[27];
    const float* b2 = (const float*)d_in[28];
    const float* W3 = (const float*)d_in[29];
    const float* b3 = (const float*)d_in[30];
    const float* Wout = (const float*)d_in[31];
    const float* bout = (const float*)d_in[32];

    const int* src_ac = (const int*)d_in[33];
    const int* dst_ac = (const int*)d_in[34];
    const int* src_cb = (const int*)d_in[35];
    const int* dst_cb = (const int*)d_in[36];
    const int* batch_c = (const int*)d_in[37];
    const int* batch_b = (const int*)d_in[38];

    const int Nx = in_sizes[0] / F;
    const int Nc = in_sizes[1] / F;
    const int Nb = in_sizes[2] / F;
    const int E1 = in_sizes[33];
    const int E2 = in_sizes[35];
    (void)n_in; (void)out_size;

    const int NT = Nc + Nb;
    const size_t ET = (size_t)E1 + E2;
    const int NMAX = (Nc > Nb ? Nc : Nb);
    const int EMAX = (E1 > E2 ? E1 : E2);
    const int SRCMAX = (Nx > Nc ? Nx : Nc);
    const size_t SUMS = 2 * NUM_G * H;
    const int perB = (NT + SORTB - 1) / SORTB;

    const size_t wordsA = 2 * ET + (size_t)(NT + 1) + NT + 256 + SUMS
                        + (size_t)(Nx + Nc) * H + (size_t)(Nc + Nb) * H;
    size_t tOff = (wordsA + 1) & ~(size_t)1;                  // 8B align t_se
    const size_t wordsB = tOff + 2 * ET + ET + (size_t)SORTB * NBLK + 257;
    const bool pathA = (ws_size >= wordsA * 4);
    const bool pathB = (ws_size >= wordsB * 4) && (perB * 4 + 1024 + 64 <= 65536);

    int* ws = (int*)d_ws;
    const size_t metaN = pathA ? 2 * ET : 2 * (size_t)EMAX;
    const int nOff = pathA ? NT : NMAX;
    int2*     meta    = (int2*)ws;
    int*      offsets = ws + metaN;
    int*      cnt     = offsets + (nOff + 1);
    int*      bsums   = cnt + nOff;
    float*    sum_c   = (float*)(bsums + 256);
    float*    sum_b   = sum_c + NUM_G * H;
    unsigned* qvp     = (unsigned*)(sum_b + NUM_G * H);
    unsigned* kskp    = qvp + (size_t)(pathA ? (Nx + Nc) : SRCMAX) * H;
    int2*     t_se    = (int2*)(ws + tOff);
    int*      t_d     = (int*)(t_se + ET);
    int*      bhist   = t_d + ET;
    int*      bucketStart = bhist + (size_t)SORTB * NBLK;

    const int nC0 = (Nc + DPW - 1) / DPW;
    const int nC1 = (Nb + DPW - 1) / DPW;

    RelP P0, P1;
    P0.We = We_ac; P0.be = be_ac; P0.batch = batch_c; P0.psum = sum_c;
    P0.Ndst = Nc; P0.offBase = 0; P0.kskBase = 0;
    P1.We = We_cb; P1.be = be_cb; P1.batch = batch_b; P1.psum = sum_b;
    P1.Ndst = Nb; P1.offBase = pathA ? Nc : 0; P1.kskBase = pathA ? Nc : 0;

    if (pathA) {
        const int w1 = (Nx + PROJ_ROWS - 1) / PROJ_ROWS;
        const int w2 = w1 + (Nc + PROJ_ROWS - 1) / PROJ_ROWS;
        const int w3 = w2 + (Nc + PROJ_ROWS - 1) / PROJ_ROWS;
        const int wTot = w3 + (Nb + PROJ_ROWS - 1) / PROJ_ROWS;
        ProjSec s0 = { x_x, Wq_ac, bq_ac, Wv_ac, bv_ac, qvp, Nx, 0, L2E };
        ProjSec s1 = { x_c, Wq_cb, bq_cb, Wv_cb, bv_cb, qvp + (size_t)Nx * H, Nc, w1, L2E };
        ProjSec s2 = { x_c, Wk_ac, bk_ac, Wskip_ac, bconv_ac, kskp, Nc, w2, L2E };
        ProjSec s3 = { x_b, Wk_cb, bk_cb, Wskip_cb, bconv_cb, kskp + (size_t)Nc * H, Nb, w3, L2E };
        const int projB = (wTot + 3) / 4;

        if (pathB) {
            hipMemsetAsync(sum_c, 0, SUMS * sizeof(float), stream);
            // proj only (histBlocks = 0)
            hist_proj_kernel<<<projB, 256, 0, stream>>>(
                dst_ac, 0, dst_cb, 0, Nc, cnt, 0, s0, s1, s2, s3, wTot);
            bhist_kernel<<<NBLK, 256, 0, stream>>>(dst_ac, E1, dst_cb, E2, Nc, perB, bhist);
            btot_scan_kernel<<<1, 256, 0, stream>>>(bhist, bucketStart);
            bhist_scan_kernel<<<SORTB, 256, 0, stream>>>(bhist, bucketStart);
            bscatter_kernel<<<NBLK, 256, 0, stream>>>(
                src_ac, dst_ac, ea_ac, E1, src_cb, dst_cb, ea_cb, E2,
                Nc, Nx, perB, bhist, t_se, t_d);
            bucket_sort_kernel<<<SORTB, 256, (perB + 257) * sizeof(int), stream>>>(
                t_se, t_d, bucketStart, NT, perB, offsets, meta);
        } else {
            hipMemsetAsync(cnt, 0, (size_t)(NT + 256 + SUMS) * sizeof(int), stream);
            const int nScan = (NT + 2047) / 2048;
            const int EB = (int)((ET + 255) / 256);
            hist_proj_kernel<<<EB + projB, 256, 0, stream>>>(
                dst_ac, E1, dst_cb, E2, Nc, cnt, EB, s0, s1, s2, s3, wTot);
            scan_partial<<<nScan, 256, 0, stream>>>(cnt, bsums, NT);
            scan_bsums<<<1, 256, 0, stream>>>(bsums, nScan);
            scan_final<<<nScan, 256, 0, stream>>>(cnt, bsums, offsets, NT);
            scatter_part_kernel<<<2048, 256, 0, stream>>>(
                src_ac, dst_ac, ea_ac, E1, src_cb, dst_cb, ea_cb, E2,
                Nc, Nx, NT, cnt, meta);
        }

        const int nW = nC0 + nC1;
        aggregate_v4<<<(nW + 3) / 4, 256, 0, stream>>>(
            P0, P1, qvp, kskp, offsets, meta, nC0, nW);
    } else {
        hipMemsetAsync(sum_c, 0, SUMS * sizeof(float), stream);
        for (int rel = 0; rel < 2; ++rel) {
            const int n = rel ? Nb : Nc;
            const int E = rel ? E2 : E1;
            const int Ns = rel ? Nc : Nx;
            const int* srcA = rel ? src_cb : src_ac;
            const int* dstA = rel ? dst_cb : dst_ac;
            const float* eaA = rel ? ea_cb : ea_ac;
            const float* xs = rel ? x_c : x_x;
            const float* xd = rel ? x_b : x_c;
            const float* Wq = rel ? Wq_cb : Wq_ac; const float* bq = rel ? bq_cb : bq_ac;
            const float* Wv = rel ? Wv_cb : Wv_ac; const float* bv = rel ? bv_cb : bv_ac;
            const float* Wk = rel ? Wk_cb : Wk_ac; const float* bk = rel ? bk_cb : bk_ac;
            const float* Wsk = rel ? Wskip_cb : Wskip_ac;
            const float* bcv = rel ? bconv_cb : bconv_ac;
            const int nScan = (n + 2047) / 2048;
            hipMemsetAsync(cnt, 0, n * sizeof(int), stream);
            const int w1 = (Ns + PROJ_ROWS - 1) / PROJ_ROWS;
            const int wTot = w1 + (n + PROJ_ROWS - 1) / PROJ_ROWS;
            ProjSec s0 = { xs, Wq, bq, Wv, bv, qvp, Ns, 0, L2E };
            ProjSec s1 = { xs, Wq, bq, Wv, bv, qvp, 0, w1, L2E };
            ProjSec s2 = { xd, Wk, bk, Wsk, bcv, kskp, n, w1, L2E };
            ProjSec s3 = { xd, Wk, bk, Wsk, bcv, kskp, 0, wTot, L2E };
            const int EB = (E + 255) / 256;
            const int projB = (wTot + 3) / 4;
            hist_proj_kernel<<<EB + projB, 256, 0, stream>>>(
                dstA, E, dstA, 0, 0, cnt, EB, s0, s1, s2, s3, wTot);
            scan_partial<<<nScan, 256, 0, stream>>>(cnt, bsums, n);
            scan_bsums<<<1, 256, 0, stream>>>(bsums, nScan);
            scan_final<<<nScan, 256, 0, stream>>>(cnt, bsums, offsets, n);
            scatter_part_kernel<<<2048, 256, 0, stream>>>(
                srcA, dstA, eaA, E, srcA, dstA, eaA, 0, 0, 0, n, cnt, meta);
            RelP PR = rel ? P1 : P0;
            const int nCr = rel ? nC1 : nC0;
            aggregate_v4<<<(nCr + 3) / 4, 256, 0, stream>>>(
                PR, PR, qvp, kskp, offsets, meta, nCr, nCr);
        }
    }

    mlp_kernel<<<NUM_G, 64, 0, stream>>>(
        sum_c, sum_b, batch_c, Nc, batch_b, Nb,
        W1, b1, W2, b2, W3, b3, Wout, bout, (float*)d_out);
}